// Round 8
// baseline (1593.159 us; speedup 1.0000x reference)
//
#include <hip/hip_runtime.h>
#include <math.h>

// M3GNet-like GNN forward. N=10000 nodes, E=160000 edges, T=1200000 triplets,
// D=256, DM=64, H=1024, L=3, output = scalar mean energy (fp32).
//
// R7:
//  - k_scatter: pack (src, cos-bits) into one int2 scattered store (was 3
//    separate 4B scatters -> write-allocate amplification, 156 MB writes);
//    eids now filled coalesced from rowp by k_fill_eids.
//  - k_ffn2s: grid flipped to (cols, rows, kq) so the 4 column-blocks that
//    share the same 64 h-rows are dispatched consecutively -> h fetched from
//    HBM once, re-reads hit L2 (FETCH was 84 MB = ~2x h).

#define DM 64
#define DMODEL 256
#define HDIM 1024

__global__ void k_embed(const int* __restrict__ an, const float* __restrict__ emb,
                        float* __restrict__ x) {
    int n = blockIdx.x;
    int d = threadIdx.x;          // blockDim = 256
    x[n * DMODEL + d] = emb[an[n] * DMODEL + d];
}

__global__ void k_edge_geom(const float* __restrict__ r, float* __restrict__ bl,
                            float* __restrict__ rn, int E) {
    int e = blockIdx.x * blockDim.x + threadIdx.x;
    if (e >= E) return;
    float a = r[e * 3 + 0], b = r[e * 3 + 1], c = r[e * 3 + 2];
    float l = sqrtf(a * a + b * b + c * c);
    bl[e] = l;
    float inv = 1.0f / l;
    // note: reference uses -r/|r| for both operands of the dot; signs cancel.
    rn[e * 3 + 0] = a * inv;
    rn[e * 3 + 1] = b * inv;
    rn[e * 3 + 2] = c * inv;
}

__global__ void k_hist(const int* __restrict__ idx, int* __restrict__ cnt, int M) {
    int t = blockIdx.x * blockDim.x + threadIdx.x;
    if (t < M) atomicAdd(&cnt[idx[t]], 1);
}

// ---- 3-phase exclusive scan of cnt[M] -> rowp[M+1] (generic) ----
__global__ __launch_bounds__(256) void k_scan_part(
    const int* __restrict__ cnt, int* __restrict__ bsum, int M) {
    __shared__ int sm[4];
    int tid = threadIdx.x;
    int i = blockIdx.x * 256 + tid;
    int v = (i < M) ? cnt[i] : 0;
    for (int off = 32; off > 0; off >>= 1) v += __shfl_xor(v, off, 64);
    if ((tid & 63) == 0) sm[tid >> 6] = v;
    __syncthreads();
    if (tid == 0) bsum[blockIdx.x] = sm[0] + sm[1] + sm[2] + sm[3];
}

__global__ __launch_bounds__(1024) void k_scan_mid(int* __restrict__ bsum, int nb) {
    __shared__ int sm[1024];
    int tid = threadIdx.x;
    int v = (tid < nb) ? bsum[tid] : 0;
    sm[tid] = v;
    __syncthreads();
    for (int off = 1; off < 1024; off <<= 1) {
        int u = (tid >= off) ? sm[tid - off] : 0;
        __syncthreads();
        sm[tid] += u;
        __syncthreads();
    }
    if (tid < nb) bsum[tid] = sm[tid] - v;   // inclusive -> exclusive
}

__global__ __launch_bounds__(256) void k_scan_final(
    const int* __restrict__ cnt, const int* __restrict__ bsum,
    int* __restrict__ rowp, int M, int total) {
    __shared__ int sm[256];
    int tid = threadIdx.x;
    int i = blockIdx.x * 256 + tid;
    int v = (i < M) ? cnt[i] : 0;
    sm[tid] = v;
    __syncthreads();
    for (int off = 1; off < 256; off <<= 1) {
        int u = (tid >= off) ? sm[tid - off] : 0;
        __syncthreads();
        sm[tid] += u;
        __syncthreads();
    }
    if (i < M) rowp[i] = bsum[blockIdx.x] + sm[tid] - v;
    if (i == 0) rowp[M] = total;
}

// scatter triplets into segment order; ONE packed 8B store per triplet:
// (src, float-bits-of-cos).
__global__ void k_scatter(const int* __restrict__ ts, const int* __restrict__ td,
                          const int* __restrict__ rowp, int* __restrict__ cursor,
                          const float* __restrict__ rn,
                          int2* __restrict__ packed, int T) {
    int t = blockIdx.x * blockDim.x + threadIdx.x;
    if (t >= T) return;
    int a = ts[t], b = td[t];
    float d = rn[a * 3 + 0] * rn[b * 3 + 0]
            + rn[a * 3 + 1] * rn[b * 3 + 1]
            + rn[a * 3 + 2] * rn[b * 3 + 2];
    d = fminf(1.0f, fmaxf(-1.0f, d));
    int pos = rowp[b] + atomicAdd(&cursor[b], 1);
    packed[pos] = make_int2(a, __float_as_int(d));
}

// coalesced-ish fill of eids from rowp (thread per edge, avg 7.5 writes).
__global__ void k_fill_eids(const int* __restrict__ rowp, int* __restrict__ eids,
                            int E) {
    int e = blockIdx.x * blockDim.x + threadIdx.x;
    if (e >= E) return;
    int beg = rowp[e], end = rowp[e + 1];
    for (int p = beg; p < end; ++p) eids[p] = e;
}

// scatter edge ids into node order (CSR by gd)
__global__ void k_escatter(const int* __restrict__ gd, const int* __restrict__ erowp,
                           int* __restrict__ cursor, int* __restrict__ eord, int E) {
    int e = blockIdx.x * blockDim.x + threadIdx.x;
    if (e >= E) return;
    int n = gd[e];
    int pos = erowp[n] + atomicAdd(&cursor[n], 1);
    eord[pos] = e;
}

// xs = x@Wsrc + bsrc ; xd = x@Wdst + bdst   (wave per node, lane = dm)
__global__ __launch_bounds__(256) void k_node_proj(
    const float* __restrict__ x,
    const float* __restrict__ Ws, const float* __restrict__ bs,
    const float* __restrict__ Wd, const float* __restrict__ bd,
    float* __restrict__ xs, float* __restrict__ xd, int N) {
    int lane = threadIdx.x & 63;
    int n = blockIdx.x * 4 + (threadIdx.x >> 6);
    if (n >= N) return;
    const float* xr = x + (size_t)n * DMODEL;
    float as = 0.f, ad = 0.f;
    for (int d = 0; d < DMODEL; ++d) {
        float xv = xr[d];
        as = fmaf(xv, Ws[d * DM + lane], as);
        ad = fmaf(xv, Wd[d * DM + lane], ad);
    }
    xs[n * DM + lane] = as + bs[lane];
    xd[n * DM + lane] = ad + bd[lane];
}

// xij[e][m] = RBF(bl[e]) @ Wedge + bedge + xs[g_src[e]] + xd[g_dst[e]]
// 64-edge x 64-col tile, k-major LDS, 4x4 register blocking, float4 reads.
__global__ __launch_bounds__(256) void k_xij(
    const float* __restrict__ bl,
    const float* __restrict__ We, const float* __restrict__ be,
    const float* __restrict__ xs, const float* __restrict__ xd,
    const int* __restrict__ gs, const int* __restrict__ gd,
    float* __restrict__ xij, int E) {
    __shared__ float A[32][68];   // A[kk][edge]
    __shared__ float B[32][68];   // B[kk][col]
    int tid = threadIdx.x;
    int e0 = blockIdx.x * 64;
    int ty = tid >> 4, tx = tid & 15;
    int row = tid & 63;           // edge row this thread stages
    int kbase = tid >> 6;         // 0..3
    const float step = 8.0f / 255.0f;
    const float gamma = (255.0f / 8.0f) * (255.0f / 8.0f);
    int erow = e0 + row;
    float blv = (erow < E) ? bl[erow] : 0.f;
    float acc[4][4] = {};
    for (int k0 = 0; k0 < DMODEL; k0 += 32) {
        #pragma unroll
        for (int i = 0; i < 8; ++i) {
            int kk = i * 4 + kbase;
            float c = (float)(k0 + kk) * step;
            float dd = blv - c;
            A[kk][row] = __expf(-gamma * dd * dd);
            B[kk][row] = We[(size_t)(k0 + kk) * DM + row];
        }
        __syncthreads();
        for (int kk = 0; kk < 32; ++kk) {
            float4 av = *(const float4*)&A[kk][ty * 4];
            float4 bv = *(const float4*)&B[kk][tx * 4];
            float a4[4] = {av.x, av.y, av.z, av.w};
            float b4[4] = {bv.x, bv.y, bv.z, bv.w};
            for (int i = 0; i < 4; ++i)
                for (int j = 0; j < 4; ++j)
                    acc[i][j] = fmaf(a4[i], b4[j], acc[i][j]);
        }
        __syncthreads();
    }
    int m0 = tx * 4;
    float4 bev = *(const float4*)&be[m0];
    for (int i = 0; i < 4; ++i) {
        int e = e0 + ty * 4 + i;
        if (e >= E) continue;
        int s = gs[e], d2 = gd[e];
        float4 xsv = *(const float4*)&xs[(size_t)s * DM + m0];
        float4 xdv = *(const float4*)&xd[(size_t)d2 * DM + m0];
        float4 o;
        o.x = acc[i][0] + xsv.x + xdv.x + bev.x;
        o.y = acc[i][1] + xsv.y + xdv.y + bev.y;
        o.z = acc[i][2] + xsv.z + xdv.z + bev.z;
        o.w = acc[i][3] + xsv.w + xdv.w + bev.w;
        *(float4*)&xij[(size_t)e * DM + m0] = o;
    }
}

// thread per triplet: logit[p] = sum_k silu(T_k(cos) + xs_row[k] + xe_row[k]) * attn[k]
// Chebyshev recurrence; float4 row loads; no cross-lane ops.
__global__ __launch_bounds__(256) void k_logit(
    const float* __restrict__ xij, const int2* __restrict__ packed,
    const int* __restrict__ eids,
    const float* __restrict__ attn_l, float* __restrict__ logits, int T) {
    int p = blockIdx.x * 256 + threadIdx.x;
    if (p >= T) return;
    int2 pk = packed[p];
    int s = pk.x;
    float c = __int_as_float(pk.y);
    int e = eids[p];
    float c2 = 2.0f * c;
    const float4* xsr = (const float4*)(xij + (size_t)s * DM);
    const float4* xer = (const float4*)(xij + (size_t)e * DM);
    float t0 = 1.0f, t1 = c;
    float acc = 0.f;
    #pragma unroll
    for (int j = 0; j < 16; ++j) {
        float4 a4 = xsr[j];
        float4 b4 = xer[j];
        float u[4] = {a4.x + b4.x, a4.y + b4.y, a4.z + b4.z, a4.w + b4.w};
        #pragma unroll
        for (int q = 0; q < 4; ++q) {
            int k = j * 4 + q;
            float tk;
            if (k == 0)      tk = 1.0f;
            else if (k == 1) tk = c;
            else { tk = fmaf(c2, t1, -t0); t0 = t1; t1 = tk; }
            float v = tk + u[q];
            float sl = v / (1.0f + __expf(-v));
            acc = fmaf(sl, attn_l[k], acc);
        }
    }
    logits[p] = acc;
}

// thread per (edge, channel-quad): softmax over segment logits + weighted
// float4 gather of source rows. Plain stores to msg (no atomics).
__global__ __launch_bounds__(256) void k_attend(
    const float* __restrict__ xij, const float* __restrict__ logits,
    const int2* __restrict__ packed, const int* __restrict__ rowp,
    float* __restrict__ msg, int E) {
    int gtid = blockIdx.x * 256 + threadIdx.x;
    int e = gtid >> 4;
    if (e >= E) return;
    int quad = gtid & 15;
    int beg = rowp[e], end = rowp[e + 1];
    float4 acc = {0.f, 0.f, 0.f, 0.f};
    if (beg < end) {
        float lm = -1e30f;
        for (int p = beg; p < end; ++p) lm = fmaxf(lm, logits[p]);
        float den = 0.f;
        for (int p = beg; p < end; ++p) {
            float w = __expf(logits[p] - lm);
            den += w;
            int s = packed[p].x;
            float4 v = *(const float4*)&xij[(size_t)s * DM + quad * 4];
            acc.x = fmaf(w, v.x, acc.x);
            acc.y = fmaf(w, v.y, acc.y);
            acc.z = fmaf(w, v.z, acc.z);
            acc.w = fmaf(w, v.w, acc.w);
        }
        float inv = 1.0f / den;
        acc.x *= inv; acc.y *= inv; acc.z *= inv; acc.w *= inv;
    }
    *(float4*)&msg[(size_t)e * DM + quad * 4] = acc;
}

// thread per (node, channel-quad): sum msg over this node's incoming edges.
__global__ __launch_bounds__(256) void k_aggregate(
    const float* __restrict__ msg, const int* __restrict__ erowp,
    const int* __restrict__ eord, float* __restrict__ ft, int N) {
    int gtid = blockIdx.x * 256 + threadIdx.x;
    int n = gtid >> 4;
    if (n >= N) return;
    int quad = gtid & 15;
    int beg = erowp[n], end = erowp[n + 1];
    float4 acc = {0.f, 0.f, 0.f, 0.f};
    for (int j = beg; j < end; ++j) {
        float4 v = *(const float4*)&msg[(size_t)eord[j] * DM + quad * 4];
        acc.x += v.x; acc.y += v.y; acc.z += v.z; acc.w += v.w;
    }
    *(float4*)&ft[(size_t)n * DM + quad * 4] = acc;
}

// h = silu(ft @ W1 + b1): 64-node x 64-hcol tile, 4x4 register blocking.
// grid (ceil(N/64), HDIM/64) = (157, 16)
__global__ __launch_bounds__(256) void k_ffn1(
    const float* __restrict__ ft, const float* __restrict__ W1,
    const float* __restrict__ b1, float* __restrict__ h, int N) {
    __shared__ float A[32][68];   // A[kk][node], k-major, +4 pad (16B-aligned rows)
    __shared__ float B[32][68];   // B[kk][col]
    int tid = threadIdx.x;
    int n0 = blockIdx.x * 64;
    int c0 = blockIdx.y * 64;
    int ty = tid >> 4, tx = tid & 15;
    float acc[4][4] = {};
    for (int k0 = 0; k0 < DM; k0 += 32) {
        for (int i = 0; i < 8; ++i) {
            int flat = i * 256 + tid;
            int row = flat >> 5, kk = flat & 31;
            int n = n0 + row;
            A[kk][row] = (n < N) ? ft[(size_t)n * DM + k0 + kk] : 0.f;
        }
        for (int i = 0; i < 8; ++i) {
            int flat = i * 256 + tid;
            int kk = flat >> 6, col = flat & 63;
            B[kk][col] = W1[(size_t)(k0 + kk) * HDIM + c0 + col];
        }
        __syncthreads();
        for (int kk = 0; kk < 32; ++kk) {
            float4 av = *(const float4*)&A[kk][ty * 4];
            float4 bv = *(const float4*)&B[kk][tx * 4];
            float a4[4] = {av.x, av.y, av.z, av.w};
            float b4[4] = {bv.x, bv.y, bv.z, bv.w};
            for (int i = 0; i < 4; ++i)
                for (int j = 0; j < 4; ++j)
                    acc[i][j] = fmaf(a4[i], b4[j], acc[i][j]);
        }
        __syncthreads();
    }
    float4 bb = *(const float4*)&b1[c0 + tx * 4];
    float b4[4] = {bb.x, bb.y, bb.z, bb.w};
    for (int i = 0; i < 4; ++i) {
        int n = n0 + ty * 4 + i;
        if (n >= N) continue;
        float4 o;
        float v0 = acc[i][0] + b4[0], v1 = acc[i][1] + b4[1];
        float v2 = acc[i][2] + b4[2], v3 = acc[i][3] + b4[3];
        o.x = v0 / (1.0f + __expf(-v0));
        o.y = v1 / (1.0f + __expf(-v1));
        o.z = v2 / (1.0f + __expf(-v2));
        o.w = v3 / (1.0f + __expf(-v3));
        *(float4*)&h[(size_t)n * HDIM + c0 + tx * 4] = o;
    }
}

// split-K ffn2: xpart[kq][n][c] = h[:, kq*256:(kq+1)*256] @ W2[chunk]
// grid (DMODEL/64, ceil(N/64), 4): column-block is FASTEST so the 4 blocks
// sharing the same 64 h-rows are co-scheduled -> h fetched once, L2 reuse.
__global__ __launch_bounds__(256) void k_ffn2s(
    const float* __restrict__ h, const float* __restrict__ W2,
    float* __restrict__ xpart, int N) {
    __shared__ float A[32][68];
    __shared__ float B[32][68];
    int tid = threadIdx.x;
    int c0 = blockIdx.x * 64;
    int n0 = blockIdx.y * 64;
    int kq = blockIdx.z;
    int kstart = kq * (HDIM / 4);
    float* xp = xpart + (size_t)kq * N * DMODEL;
    int ty = tid >> 4, tx = tid & 15;
    float acc[4][4] = {};
    for (int k0 = kstart; k0 < kstart + HDIM / 4; k0 += 32) {
        for (int i = 0; i < 8; ++i) {
            int flat = i * 256 + tid;
            int row = flat >> 5, kk = flat & 31;
            int n = n0 + row;
            A[kk][row] = (n < N) ? h[(size_t)n * HDIM + k0 + kk] : 0.f;
        }
        for (int i = 0; i < 8; ++i) {
            int flat = i * 256 + tid;
            int kk = flat >> 6, col = flat & 63;
            B[kk][col] = W2[(size_t)(k0 + kk) * DMODEL + c0 + col];
        }
        __syncthreads();
        for (int kk = 0; kk < 32; ++kk) {
            float4 av = *(const float4*)&A[kk][ty * 4];
            float4 bv = *(const float4*)&B[kk][tx * 4];
            float a4[4] = {av.x, av.y, av.z, av.w};
            float b4[4] = {bv.x, bv.y, bv.z, bv.w};
            for (int i = 0; i < 4; ++i)
                for (int j = 0; j < 4; ++j)
                    acc[i][j] = fmaf(a4[i], b4[j], acc[i][j]);
        }
        __syncthreads();
    }
    for (int i = 0; i < 4; ++i) {
        int n = n0 + ty * 4 + i;
        if (n >= N) continue;
        float4 o = {acc[i][0], acc[i][1], acc[i][2], acc[i][3]};
        *(float4*)&xp[(size_t)n * DMODEL + c0 + tx * 4] = o;
    }
}

// x[n][c] = sum_kq xpart[kq][n][c] + b2[c]   (thread per float4)
__global__ __launch_bounds__(256) void k_ffn2_reduce(
    const float* __restrict__ xpart, const float* __restrict__ b2,
    float* __restrict__ x, int N) {
    int gtid = blockIdx.x * 256 + threadIdx.x;
    int nq = N * (DMODEL / 4);
    if (gtid >= nq) return;
    int c4 = gtid & (DMODEL / 4 - 1);
    size_t idx = (size_t)gtid * 4;
    size_t stride = (size_t)N * DMODEL;
    float4 a = *(const float4*)&xpart[idx];
    float4 b = *(const float4*)&xpart[idx + stride];
    float4 c = *(const float4*)&xpart[idx + 2 * stride];
    float4 d = *(const float4*)&xpart[idx + 3 * stride];
    float4 bb = *(const float4*)&b2[c4 * 4];
    float4 o;
    o.x = a.x + b.x + c.x + d.x + bb.x;
    o.y = a.y + b.y + c.y + d.y + bb.y;
    o.z = a.z + b.z + c.z + d.z + bb.z;
    o.w = a.w + b.w + c.w + d.w + bb.w;
    *(float4*)&x[idx] = o;
}

// grid-stride dot(x, tiled Wfc) with per-block LDS reduction -> 1 atomic/block.
__global__ __launch_bounds__(256) void k_out_reduce(
    const float* __restrict__ x, const float* __restrict__ Wfc,
    float* __restrict__ acc, int NT) {
    __shared__ float sm[4];
    int tid = threadIdx.x;
    float v = 0.f;
    for (int i = blockIdx.x * blockDim.x + tid; i < NT; i += gridDim.x * blockDim.x)
        v = fmaf(x[i], Wfc[i & (DMODEL - 1)], v);
    for (int off = 32; off > 0; off >>= 1) v += __shfl_xor(v, off, 64);
    if ((tid & 63) == 0) sm[tid >> 6] = v;
    __syncthreads();
    if (tid == 0) {
        float s = sm[0] + sm[1] + sm[2] + sm[3];
        atomicAdd(acc, s);
    }
}

__global__ void k_out_final(const float* __restrict__ acc, const float* __restrict__ bfc,
                            float* __restrict__ out, float invN) {
    out[0] = acc[0] * invN + bfc[0];
}

extern "C" void kernel_launch(void* const* d_in, const int* in_sizes, int n_in,
                              void* d_out, int out_size, void* d_ws, size_t ws_size,
                              hipStream_t stream) {
    const int*   an    = (const int*)d_in[0];
    const int*   gs    = (const int*)d_in[1];
    const int*   gd    = (const int*)d_in[2];
    const int*   ts    = (const int*)d_in[3];
    const int*   td    = (const int*)d_in[4];
    const float* r     = (const float*)d_in[5];
    const float* emb   = (const float*)d_in[6];
    const float* Wsrc  = (const float*)d_in[7];
    const float* bsrc  = (const float*)d_in[8];
    const float* Wdst  = (const float*)d_in[9];
    const float* bdst  = (const float*)d_in[10];
    const float* Wedge = (const float*)d_in[11];
    const float* bedge = (const float*)d_in[12];
    const float* attn  = (const float*)d_in[13];
    const float* W1    = (const float*)d_in[14];
    const float* b1    = (const float*)d_in[15];
    const float* W2    = (const float*)d_in[16];
    const float* b2    = (const float*)d_in[17];
    const float* Wfc   = (const float*)d_in[18];
    const float* bfc   = (const float*)d_in[19];

    const int N = in_sizes[0];
    const int E = in_sizes[1];
    const int T = in_sizes[3];

    char* w = (char*)d_ws;
    size_t off = 0;
    auto alloc = [&](size_t elems) {
        void* p = w + off;
        off += ((elems * 4 + 255) / 256) * 256;
        return p;
    };
    float* x      = (float*)alloc((size_t)N * DMODEL);
    float* rn     = (float*)alloc((size_t)E * 3);
    float* bl     = (float*)alloc((size_t)E);
    int*   cnt    = (int*)  alloc((size_t)E);
    int*   rowp   = (int*)  alloc((size_t)E + 1);
    int*   bsum   = (int*)  alloc(1024);
    int2*  packed = (int2*) alloc((size_t)T * 2);
    int*   eids   = (int*)  alloc((size_t)T);
    float* logits = (float*)alloc((size_t)T);
    int*   ecnt   = (int*)  alloc((size_t)N);
    int*   erowp  = (int*)  alloc((size_t)N + 1);
    int*   eord   = (int*)  alloc((size_t)E);
    float* xs     = (float*)alloc((size_t)N * DM);
    float* xd     = (float*)alloc((size_t)N * DM);
    float* xij    = (float*)alloc((size_t)E * DM);
    float* ft     = (float*)alloc((size_t)N * DM);
    float* h      = (float*)alloc((size_t)N * HDIM);
    float* accs   = (float*)alloc(16);
    float* msg    = h;     // aliased: msg (attend->aggregate) dies before ffn1 writes h
    float* xpart  = xij;   // aliased: xij dead after k_attend; 4*N*DMODEL == E*DM
    (void)ws_size; (void)n_in; (void)out_size;

    const int nbScanE = (E + 255) / 256;   // 625 <= 1024
    const int nbScanN = (N + 255) / 256;   // 40   <= 1024

    // ---- setup (layer-invariant) ----
    k_embed<<<N, 256, 0, stream>>>(an, emb, x);
    k_edge_geom<<<(E + 255) / 256, 256, 0, stream>>>(r, bl, rn, E);
    // triplet CSR by t_dst
    hipMemsetAsync(cnt, 0, (size_t)E * 4, stream);
    k_hist<<<(T + 255) / 256, 256, 0, stream>>>(td, cnt, T);
    k_scan_part<<<nbScanE, 256, 0, stream>>>(cnt, bsum, E);
    k_scan_mid<<<1, 1024, 0, stream>>>(bsum, nbScanE);
    k_scan_final<<<nbScanE, 256, 0, stream>>>(cnt, bsum, rowp, E, T);
    hipMemsetAsync(cnt, 0, (size_t)E * 4, stream);
    k_scatter<<<(T + 255) / 256, 256, 0, stream>>>(ts, td, rowp, cnt, rn,
                                                   packed, T);
    k_fill_eids<<<(E + 255) / 256, 256, 0, stream>>>(rowp, eids, E);
    // edge CSR by gd
    hipMemsetAsync(ecnt, 0, (size_t)N * 4, stream);
    k_hist<<<(E + 255) / 256, 256, 0, stream>>>(gd, ecnt, E);
    k_scan_part<<<nbScanN, 256, 0, stream>>>(ecnt, bsum, N);
    k_scan_mid<<<1, 1024, 0, stream>>>(bsum, nbScanN);
    k_scan_final<<<nbScanN, 256, 0, stream>>>(ecnt, bsum, erowp, N, E);
    hipMemsetAsync(ecnt, 0, (size_t)N * 4, stream);
    k_escatter<<<(E + 255) / 256, 256, 0, stream>>>(gd, erowp, ecnt, eord, E);

    // ---- layers ----
    for (int l = 0; l < 3; ++l) {
        k_node_proj<<<(N + 3) / 4, 256, 0, stream>>>(
            x, Wsrc + l * DMODEL * DM, bsrc + l * DM,
            Wdst + l * DMODEL * DM, bdst + l * DM, xs, xd, N);
        k_xij<<<(E + 63) / 64, 256, 0, stream>>>(
            bl, Wedge + l * DMODEL * DM, bedge + l * DM, xs, xd, gs, gd, xij, E);
        k_logit<<<(T + 255) / 256, 256, 0, stream>>>(
            xij, packed, eids, attn + l * DM, logits, T);
        k_attend<<<(E * 16 + 255) / 256, 256, 0, stream>>>(
            xij, logits, packed, rowp, msg, E);
        k_aggregate<<<(N * 16 + 255) / 256, 256, 0, stream>>>(
            msg, erowp, eord, ft, N);
        k_ffn1<<<dim3((N + 63) / 64, HDIM / 64), 256, 0, stream>>>(
            ft, W1 + l * DM * HDIM, b1 + l * HDIM, h, N);
        k_ffn2s<<<dim3(DMODEL / 64, (N + 63) / 64, 4), 256, 0, stream>>>(
            h, W2 + l * HDIM * DMODEL, xpart, N);
        k_ffn2_reduce<<<(N * DMODEL / 4 + 255) / 256, 256, 0, stream>>>(
            xpart, b2 + l * DMODEL, x, N);
    }

    // ---- output head ----
    hipMemsetAsync(accs, 0, 4, stream);
    k_out_reduce<<<120, 256, 0, stream>>>(x, Wfc, accs, N * DMODEL);
    k_out_final<<<1, 1, 0, stream>>>(accs, bfc, (float*)d_out, 1.0f / (float)N);
}

// Round 9
// 1439.196 us; speedup vs baseline: 1.1070x; 1.1070x over previous
//
#include <hip/hip_runtime.h>
#include <math.h>

// M3GNet-like GNN forward. N=10000 nodes, E=160000 edges, T=1200000 triplets,
// D=256, DM=64, H=1024, L=3, output = scalar mean energy (fp32).
//
// R8: bf16 storage for the three big intermediates (xij, h, msg) - fp32
// compute, RNE pack on store. Threshold is 0.5125 (bf16 floor), so 32-bit
// intermediates were pure wasted bandwidth. k_ffn2 rebuilt: 32x64 tiles,
// K=1024 unsplit, 1252 blocks (~4.9/CU), bias fused, no partial round-trip.

#define DM 64
#define DMODEL 256
#define HDIM 1024

typedef unsigned short bf16_t;

__device__ __forceinline__ bf16_t f2bf(float f) {
    unsigned int u = __float_as_uint(f);
    return (bf16_t)((u + 0x7FFFu + ((u >> 16) & 1u)) >> 16);   // RNE
}
__device__ __forceinline__ float bf_lo(unsigned int u) {       // element 0 of packed pair
    return __uint_as_float(u << 16);
}
__device__ __forceinline__ float bf_hi(unsigned int u) {       // element 1
    return __uint_as_float(u & 0xFFFF0000u);
}

__global__ void k_embed(const int* __restrict__ an, const float* __restrict__ emb,
                        float* __restrict__ x) {
    int n = blockIdx.x;
    int d = threadIdx.x;          // blockDim = 256
    x[n * DMODEL + d] = emb[an[n] * DMODEL + d];
}

__global__ void k_edge_geom(const float* __restrict__ r, float* __restrict__ bl,
                            float* __restrict__ rn, int E) {
    int e = blockIdx.x * blockDim.x + threadIdx.x;
    if (e >= E) return;
    float a = r[e * 3 + 0], b = r[e * 3 + 1], c = r[e * 3 + 2];
    float l = sqrtf(a * a + b * b + c * c);
    bl[e] = l;
    float inv = 1.0f / l;
    rn[e * 3 + 0] = a * inv;
    rn[e * 3 + 1] = b * inv;
    rn[e * 3 + 2] = c * inv;
}

__global__ void k_hist(const int* __restrict__ idx, int* __restrict__ cnt, int M) {
    int t = blockIdx.x * blockDim.x + threadIdx.x;
    if (t < M) atomicAdd(&cnt[idx[t]], 1);
}

// ---- 3-phase exclusive scan of cnt[M] -> rowp[M+1] ----
__global__ __launch_bounds__(256) void k_scan_part(
    const int* __restrict__ cnt, int* __restrict__ bsum, int M) {
    __shared__ int sm[4];
    int tid = threadIdx.x;
    int i = blockIdx.x * 256 + tid;
    int v = (i < M) ? cnt[i] : 0;
    for (int off = 32; off > 0; off >>= 1) v += __shfl_xor(v, off, 64);
    if ((tid & 63) == 0) sm[tid >> 6] = v;
    __syncthreads();
    if (tid == 0) bsum[blockIdx.x] = sm[0] + sm[1] + sm[2] + sm[3];
}

__global__ __launch_bounds__(1024) void k_scan_mid(int* __restrict__ bsum, int nb) {
    __shared__ int sm[1024];
    int tid = threadIdx.x;
    int v = (tid < nb) ? bsum[tid] : 0;
    sm[tid] = v;
    __syncthreads();
    for (int off = 1; off < 1024; off <<= 1) {
        int u = (tid >= off) ? sm[tid - off] : 0;
        __syncthreads();
        sm[tid] += u;
        __syncthreads();
    }
    if (tid < nb) bsum[tid] = sm[tid] - v;
}

__global__ __launch_bounds__(256) void k_scan_final(
    const int* __restrict__ cnt, const int* __restrict__ bsum,
    int* __restrict__ rowp, int M, int total) {
    __shared__ int sm[256];
    int tid = threadIdx.x;
    int i = blockIdx.x * 256 + tid;
    int v = (i < M) ? cnt[i] : 0;
    sm[tid] = v;
    __syncthreads();
    for (int off = 1; off < 256; off <<= 1) {
        int u = (tid >= off) ? sm[tid - off] : 0;
        __syncthreads();
        sm[tid] += u;
        __syncthreads();
    }
    if (i < M) rowp[i] = bsum[blockIdx.x] + sm[tid] - v;
    if (i == 0) rowp[M] = total;
}

// scatter triplets into segment order; one packed 8B store per triplet.
__global__ void k_scatter(const int* __restrict__ ts, const int* __restrict__ td,
                          const int* __restrict__ rowp, int* __restrict__ cursor,
                          const float* __restrict__ rn,
                          int2* __restrict__ packed, int T) {
    int t = blockIdx.x * blockDim.x + threadIdx.x;
    if (t >= T) return;
    int a = ts[t], b = td[t];
    float d = rn[a * 3 + 0] * rn[b * 3 + 0]
            + rn[a * 3 + 1] * rn[b * 3 + 1]
            + rn[a * 3 + 2] * rn[b * 3 + 2];
    d = fminf(1.0f, fmaxf(-1.0f, d));
    int pos = rowp[b] + atomicAdd(&cursor[b], 1);
    packed[pos] = make_int2(a, __float_as_int(d));
}

__global__ void k_fill_eids(const int* __restrict__ rowp, int* __restrict__ eids,
                            int E) {
    int e = blockIdx.x * blockDim.x + threadIdx.x;
    if (e >= E) return;
    int beg = rowp[e], end = rowp[e + 1];
    for (int p = beg; p < end; ++p) eids[p] = e;
}

__global__ void k_escatter(const int* __restrict__ gd, const int* __restrict__ erowp,
                           int* __restrict__ cursor, int* __restrict__ eord, int E) {
    int e = blockIdx.x * blockDim.x + threadIdx.x;
    if (e >= E) return;
    int n = gd[e];
    int pos = erowp[n] + atomicAdd(&cursor[n], 1);
    eord[pos] = e;
}

// xs = x@Wsrc + bsrc ; xd = x@Wdst + bdst   (wave per node, lane = dm)
__global__ __launch_bounds__(256) void k_node_proj(
    const float* __restrict__ x,
    const float* __restrict__ Ws, const float* __restrict__ bs,
    const float* __restrict__ Wd, const float* __restrict__ bd,
    float* __restrict__ xs, float* __restrict__ xd, int N) {
    int lane = threadIdx.x & 63;
    int n = blockIdx.x * 4 + (threadIdx.x >> 6);
    if (n >= N) return;
    const float* xr = x + (size_t)n * DMODEL;
    float as = 0.f, ad = 0.f;
    for (int d = 0; d < DMODEL; ++d) {
        float xv = xr[d];
        as = fmaf(xv, Ws[d * DM + lane], as);
        ad = fmaf(xv, Wd[d * DM + lane], ad);
    }
    xs[n * DM + lane] = as + bs[lane];
    xd[n * DM + lane] = ad + bd[lane];
}

// xij[e][m] = RBF(bl[e]) @ Wedge + bedge + xs[g_src[e]] + xd[g_dst[e]]
// output packed bf16.
__global__ __launch_bounds__(256) void k_xij(
    const float* __restrict__ bl,
    const float* __restrict__ We, const float* __restrict__ be,
    const float* __restrict__ xs, const float* __restrict__ xd,
    const int* __restrict__ gs, const int* __restrict__ gd,
    bf16_t* __restrict__ xij, int E) {
    __shared__ float A[32][68];   // A[kk][edge]
    __shared__ float B[32][68];   // B[kk][col]
    int tid = threadIdx.x;
    int e0 = blockIdx.x * 64;
    int ty = tid >> 4, tx = tid & 15;
    int row = tid & 63;
    int kbase = tid >> 6;
    const float step = 8.0f / 255.0f;
    const float gamma = (255.0f / 8.0f) * (255.0f / 8.0f);
    int erow = e0 + row;
    float blv = (erow < E) ? bl[erow] : 0.f;
    float acc[4][4] = {};
    for (int k0 = 0; k0 < DMODEL; k0 += 32) {
        #pragma unroll
        for (int i = 0; i < 8; ++i) {
            int kk = i * 4 + kbase;
            float c = (float)(k0 + kk) * step;
            float dd = blv - c;
            A[kk][row] = __expf(-gamma * dd * dd);
            B[kk][row] = We[(size_t)(k0 + kk) * DM + row];
        }
        __syncthreads();
        for (int kk = 0; kk < 32; ++kk) {
            float4 av = *(const float4*)&A[kk][ty * 4];
            float4 bv = *(const float4*)&B[kk][tx * 4];
            float a4[4] = {av.x, av.y, av.z, av.w};
            float b4[4] = {bv.x, bv.y, bv.z, bv.w};
            for (int i = 0; i < 4; ++i)
                for (int j = 0; j < 4; ++j)
                    acc[i][j] = fmaf(a4[i], b4[j], acc[i][j]);
        }
        __syncthreads();
    }
    int m0 = tx * 4;
    float4 bev = *(const float4*)&be[m0];
    for (int i = 0; i < 4; ++i) {
        int e = e0 + ty * 4 + i;
        if (e >= E) continue;
        int s = gs[e], d2 = gd[e];
        float4 xsv = *(const float4*)&xs[(size_t)s * DM + m0];
        float4 xdv = *(const float4*)&xd[(size_t)d2 * DM + m0];
        ushort4 o;
        o.x = f2bf(acc[i][0] + xsv.x + xdv.x + bev.x);
        o.y = f2bf(acc[i][1] + xsv.y + xdv.y + bev.y);
        o.z = f2bf(acc[i][2] + xsv.z + xdv.z + bev.z);
        o.w = f2bf(acc[i][3] + xsv.w + xdv.w + bev.w);
        *(ushort4*)&xij[(size_t)e * DM + m0] = o;
    }
}

// thread per triplet: Chebyshev recurrence + silu dot; bf16 row gathers
// (128B/row, was 256B).
__global__ __launch_bounds__(256) void k_logit(
    const bf16_t* __restrict__ xij, const int2* __restrict__ packed,
    const int* __restrict__ eids,
    const float* __restrict__ attn_l, float* __restrict__ logits, int T) {
    int p = blockIdx.x * 256 + threadIdx.x;
    if (p >= T) return;
    int2 pk = packed[p];
    int s = pk.x;
    float c = __int_as_float(pk.y);
    int e = eids[p];
    float c2 = 2.0f * c;
    const uint4* xsr = (const uint4*)(xij + (size_t)s * DM);   // 8 bf16/uint4
    const uint4* xer = (const uint4*)(xij + (size_t)e * DM);
    float t0 = 1.0f, t1 = c;
    float acc = 0.f;
    #pragma unroll
    for (int j = 0; j < 8; ++j) {
        uint4 a4 = xsr[j];
        uint4 b4 = xer[j];
        unsigned int au[4] = {a4.x, a4.y, a4.z, a4.w};
        unsigned int bu[4] = {b4.x, b4.y, b4.z, b4.w};
        #pragma unroll
        for (int q = 0; q < 4; ++q) {
            float us[2] = {bf_lo(au[q]) + bf_lo(bu[q]),
                           bf_hi(au[q]) + bf_hi(bu[q])};
            #pragma unroll
            for (int m = 0; m < 2; ++m) {
                int k = j * 8 + q * 2 + m;
                float tk;
                if (k == 0)      tk = 1.0f;
                else if (k == 1) tk = c;
                else { tk = fmaf(c2, t1, -t0); t0 = t1; t1 = tk; }
                float v = tk + us[m];
                float sl = v / (1.0f + __expf(-v));
                acc = fmaf(sl, attn_l[k], acc);
            }
        }
    }
    logits[p] = acc;
}

// thread per (edge, channel-quad): softmax + weighted bf16 gather; bf16 store.
__global__ __launch_bounds__(256) void k_attend(
    const bf16_t* __restrict__ xij, const float* __restrict__ logits,
    const int2* __restrict__ packed, const int* __restrict__ rowp,
    bf16_t* __restrict__ msg, int E) {
    int gtid = blockIdx.x * 256 + threadIdx.x;
    int e = gtid >> 4;
    if (e >= E) return;
    int quad = gtid & 15;
    int beg = rowp[e], end = rowp[e + 1];
    float a0 = 0.f, a1 = 0.f, a2 = 0.f, a3 = 0.f;
    if (beg < end) {
        float lm = -1e30f;
        for (int p = beg; p < end; ++p) lm = fmaxf(lm, logits[p]);
        float den = 0.f;
        for (int p = beg; p < end; ++p) {
            float w = __expf(logits[p] - lm);
            den += w;
            int s = packed[p].x;
            uint2 uv = *(const uint2*)&xij[(size_t)s * DM + quad * 4];
            a0 = fmaf(w, bf_lo(uv.x), a0);
            a1 = fmaf(w, bf_hi(uv.x), a1);
            a2 = fmaf(w, bf_lo(uv.y), a2);
            a3 = fmaf(w, bf_hi(uv.y), a3);
        }
        float inv = 1.0f / den;
        a0 *= inv; a1 *= inv; a2 *= inv; a3 *= inv;
    }
    ushort4 o = {f2bf(a0), f2bf(a1), f2bf(a2), f2bf(a3)};
    *(ushort4*)&msg[(size_t)e * DM + quad * 4] = o;
}

// thread per (node, channel-quad): sum bf16 msg over incoming edges -> fp32 ft.
__global__ __launch_bounds__(256) void k_aggregate(
    const bf16_t* __restrict__ msg, const int* __restrict__ erowp,
    const int* __restrict__ eord, float* __restrict__ ft, int N) {
    int gtid = blockIdx.x * 256 + threadIdx.x;
    int n = gtid >> 4;
    if (n >= N) return;
    int quad = gtid & 15;
    int beg = erowp[n], end = erowp[n + 1];
    float a0 = 0.f, a1 = 0.f, a2 = 0.f, a3 = 0.f;
    for (int j = beg; j < end; ++j) {
        uint2 uv = *(const uint2*)&msg[(size_t)eord[j] * DM + quad * 4];
        a0 += bf_lo(uv.x); a1 += bf_hi(uv.x);
        a2 += bf_lo(uv.y); a3 += bf_hi(uv.y);
    }
    float4 o = {a0, a1, a2, a3};
    *(float4*)&ft[(size_t)n * DM + quad * 4] = o;
}

// h = silu(ft @ W1 + b1), h stored bf16. grid (157, 16).
__global__ __launch_bounds__(256) void k_ffn1(
    const float* __restrict__ ft, const float* __restrict__ W1,
    const float* __restrict__ b1, bf16_t* __restrict__ h, int N) {
    __shared__ float A[32][68];
    __shared__ float B[32][68];
    int tid = threadIdx.x;
    int n0 = blockIdx.x * 64;
    int c0 = blockIdx.y * 64;
    int ty = tid >> 4, tx = tid & 15;
    float acc[4][4] = {};
    for (int k0 = 0; k0 < DM; k0 += 32) {
        for (int i = 0; i < 8; ++i) {
            int flat = i * 256 + tid;
            int row = flat >> 5, kk = flat & 31;
            int n = n0 + row;
            A[kk][row] = (n < N) ? ft[(size_t)n * DM + k0 + kk] : 0.f;
        }
        for (int i = 0; i < 8; ++i) {
            int flat = i * 256 + tid;
            int kk = flat >> 6, col = flat & 63;
            B[kk][col] = W1[(size_t)(k0 + kk) * HDIM + c0 + col];
        }
        __syncthreads();
        for (int kk = 0; kk < 32; ++kk) {
            float4 av = *(const float4*)&A[kk][ty * 4];
            float4 bv = *(const float4*)&B[kk][tx * 4];
            float a4[4] = {av.x, av.y, av.z, av.w};
            float b4[4] = {bv.x, bv.y, bv.z, bv.w};
            for (int i = 0; i < 4; ++i)
                for (int j = 0; j < 4; ++j)
                    acc[i][j] = fmaf(a4[i], b4[j], acc[i][j]);
        }
        __syncthreads();
    }
    float4 bb = *(const float4*)&b1[c0 + tx * 4];
    float b4[4] = {bb.x, bb.y, bb.z, bb.w};
    for (int i = 0; i < 4; ++i) {
        int n = n0 + ty * 4 + i;
        if (n >= N) continue;
        float v0 = acc[i][0] + b4[0], v1 = acc[i][1] + b4[1];
        float v2 = acc[i][2] + b4[2], v3 = acc[i][3] + b4[3];
        ushort4 o;
        o.x = f2bf(v0 / (1.0f + __expf(-v0)));
        o.y = f2bf(v1 / (1.0f + __expf(-v1)));
        o.z = f2bf(v2 / (1.0f + __expf(-v2)));
        o.w = f2bf(v3 / (1.0f + __expf(-v3)));
        *(ushort4*)&h[(size_t)n * HDIM + c0 + tx * 4] = o;
    }
}

// x = h(bf16) @ W2 + b2: 32-node x 64-col tile, K=1024 unsplit, bias fused.
// grid (DMODEL/64=4, ceil(N/32)=313) = 1252 blocks (~4.9/CU).
__global__ __launch_bounds__(256) void k_ffn2(
    const bf16_t* __restrict__ h, const float* __restrict__ W2,
    const float* __restrict__ b2, float* __restrict__ x, int N) {
    __shared__ float A[32][34];   // A[kk][row], 32 node-rows, even stride (8B ok)
    __shared__ float B[32][68];   // B[kk][col]
    int tid = threadIdx.x;
    int c0 = blockIdx.x * 64;
    int n0 = blockIdx.y * 32;
    int tx = tid & 15, ty = tid >> 4;   // ty 0..15 -> 2 rows each
    float acc[2][4] = {};
    for (int k0 = 0; k0 < HDIM; k0 += 32) {
        #pragma unroll
        for (int i = 0; i < 2; ++i) {
            int flat = i * 256 + tid;
            int row = flat >> 4;        // 0..31
            int kp = flat & 15;         // bf16-pair index
            int n = n0 + row;
            unsigned int u = 0;
            if (n < N) u = *(const unsigned int*)&h[(size_t)n * HDIM + k0 + kp * 2];
            A[kp * 2][row]     = bf_lo(u);
            A[kp * 2 + 1][row] = bf_hi(u);
        }
        #pragma unroll
        for (int i = 0; i < 2; ++i) {
            int flat = i * 256 + tid;
            int kk = flat >> 4;
            int c4 = flat & 15;
            float4 v = *(const float4*)&W2[(size_t)(k0 + kk) * DMODEL + c0 + c4 * 4];
            *(float4*)&B[kk][c4 * 4] = v;
        }
        __syncthreads();
        for (int kk = 0; kk < 32; ++kk) {
            float a0 = A[kk][ty * 2], a1 = A[kk][ty * 2 + 1];
            float4 bv = *(const float4*)&B[kk][tx * 4];
            acc[0][0] = fmaf(a0, bv.x, acc[0][0]);
            acc[0][1] = fmaf(a0, bv.y, acc[0][1]);
            acc[0][2] = fmaf(a0, bv.z, acc[0][2]);
            acc[0][3] = fmaf(a0, bv.w, acc[0][3]);
            acc[1][0] = fmaf(a1, bv.x, acc[1][0]);
            acc[1][1] = fmaf(a1, bv.y, acc[1][1]);
            acc[1][2] = fmaf(a1, bv.z, acc[1][2]);
            acc[1][3] = fmaf(a1, bv.w, acc[1][3]);
        }
        __syncthreads();
    }
    float4 bb = *(const float4*)&b2[c0 + tx * 4];
    for (int i = 0; i < 2; ++i) {
        int n = n0 + ty * 2 + i;
        if (n >= N) continue;
        float4 o = {acc[i][0] + bb.x, acc[i][1] + bb.y,
                    acc[i][2] + bb.z, acc[i][3] + bb.w};
        *(float4*)&x[(size_t)n * DMODEL + c0 + tx * 4] = o;
    }
}

// grid-stride dot(x, tiled Wfc) with per-block LDS reduction -> 1 atomic/block.
__global__ __launch_bounds__(256) void k_out_reduce(
    const float* __restrict__ x, const float* __restrict__ Wfc,
    float* __restrict__ acc, int NT) {
    __shared__ float sm[4];
    int tid = threadIdx.x;
    float v = 0.f;
    for (int i = blockIdx.x * blockDim.x + tid; i < NT; i += gridDim.x * blockDim.x)
        v = fmaf(x[i], Wfc[i & (DMODEL - 1)], v);
    for (int off = 32; off > 0; off >>= 1) v += __shfl_xor(v, off, 64);
    if ((tid & 63) == 0) sm[tid >> 6] = v;
    __syncthreads();
    if (tid == 0) {
        float s = sm[0] + sm[1] + sm[2] + sm[3];
        atomicAdd(acc, s);
    }
}

__global__ void k_out_final(const float* __restrict__ acc, const float* __restrict__ bfc,
                            float* __restrict__ out, float invN) {
    out[0] = acc[0] * invN + bfc[0];
}

extern "C" void kernel_launch(void* const* d_in, const int* in_sizes, int n_in,
                              void* d_out, int out_size, void* d_ws, size_t ws_size,
                              hipStream_t stream) {
    const int*   an    = (const int*)d_in[0];
    const int*   gs    = (const int*)d_in[1];
    const int*   gd    = (const int*)d_in[2];
    const int*   ts    = (const int*)d_in[3];
    const int*   td    = (const int*)d_in[4];
    const float* r     = (const float*)d_in[5];
    const float* emb   = (const float*)d_in[6];
    const float* Wsrc  = (const float*)d_in[7];
    const float* bsrc  = (const float*)d_in[8];
    const float* Wdst  = (const float*)d_in[9];
    const float* bdst  = (const float*)d_in[10];
    const float* Wedge = (const float*)d_in[11];
    const float* bedge = (const float*)d_in[12];
    const float* attn  = (const float*)d_in[13];
    const float* W1    = (const float*)d_in[14];
    const float* b1    = (const float*)d_in[15];
    const float* W2    = (const float*)d_in[16];
    const float* b2    = (const float*)d_in[17];
    const float* Wfc   = (const float*)d_in[18];
    const float* bfc   = (const float*)d_in[19];

    const int N = in_sizes[0];
    const int E = in_sizes[1];
    const int T = in_sizes[3];

    char* w = (char*)d_ws;
    size_t off = 0;
    auto alloc = [&](size_t bytes) {
        void* p = w + off;
        off += (bytes + 255) & ~(size_t)255;
        return p;
    };
    float*  x      = (float*) alloc((size_t)N * DMODEL * 4);
    float*  rn     = (float*) alloc((size_t)E * 3 * 4);
    float*  bl     = (float*) alloc((size_t)E * 4);
    int*    cnt    = (int*)   alloc((size_t)E * 4);
    int*    rowp   = (int*)   alloc(((size_t)E + 1) * 4);
    int*    bsum   = (int*)   alloc(4096);
    int2*   packed = (int2*)  alloc((size_t)T * 8);
    int*    eids   = (int*)   alloc((size_t)T * 4);
    float*  logits = (float*) alloc((size_t)T * 4);
    int*    ecnt   = (int*)   alloc((size_t)N * 4);
    int*    erowp  = (int*)   alloc(((size_t)N + 1) * 4);
    int*    eord   = (int*)   alloc((size_t)E * 4);
    float*  xs     = (float*) alloc((size_t)N * DM * 4);
    float*  xd     = (float*) alloc((size_t)N * DM * 4);
    bf16_t* xij    = (bf16_t*)alloc((size_t)E * DM * 2);
    bf16_t* msg    = (bf16_t*)alloc((size_t)E * DM * 2);
    float*  ft     = (float*) alloc((size_t)N * DM * 4);
    bf16_t* hb     = (bf16_t*)alloc((size_t)N * HDIM * 2);
    float*  accs   = (float*) alloc(64);
    (void)ws_size; (void)n_in; (void)out_size;

    const int nbScanE = (E + 255) / 256;   // 625 <= 1024
    const int nbScanN = (N + 255) / 256;   // 40   <= 1024

    // ---- setup (layer-invariant) ----
    k_embed<<<N, 256, 0, stream>>>(an, emb, x);
    k_edge_geom<<<(E + 255) / 256, 256, 0, stream>>>(r, bl, rn, E);
    // triplet CSR by t_dst
    hipMemsetAsync(cnt, 0, (size_t)E * 4, stream);
    k_hist<<<(T + 255) / 256, 256, 0, stream>>>(td, cnt, T);
    k_scan_part<<<nbScanE, 256, 0, stream>>>(cnt, bsum, E);
    k_scan_mid<<<1, 1024, 0, stream>>>(bsum, nbScanE);
    k_scan_final<<<nbScanE, 256, 0, stream>>>(cnt, bsum, rowp, E, T);
    hipMemsetAsync(cnt, 0, (size_t)E * 4, stream);
    k_scatter<<<(T + 255) / 256, 256, 0, stream>>>(ts, td, rowp, cnt, rn,
                                                   packed, T);
    k_fill_eids<<<(E + 255) / 256, 256, 0, stream>>>(rowp, eids, E);
    // edge CSR by gd
    hipMemsetAsync(ecnt, 0, (size_t)N * 4, stream);
    k_hist<<<(E + 255) / 256, 256, 0, stream>>>(gd, ecnt, E);
    k_scan_part<<<nbScanN, 256, 0, stream>>>(ecnt, bsum, N);
    k_scan_mid<<<1, 1024, 0, stream>>>(bsum, nbScanN);
    k_scan_final<<<nbScanN, 256, 0, stream>>>(ecnt, bsum, erowp, N, E);
    hipMemsetAsync(ecnt, 0, (size_t)N * 4, stream);
    k_escatter<<<(E + 255) / 256, 256, 0, stream>>>(gd, erowp, ecnt, eord, E);

    // ---- layers ----
    for (int l = 0; l < 3; ++l) {
        k_node_proj<<<(N + 3) / 4, 256, 0, stream>>>(
            x, Wsrc + l * DMODEL * DM, bsrc + l * DM,
            Wdst + l * DMODEL * DM, bdst + l * DM, xs, xd, N);
        k_xij<<<(E + 63) / 64, 256, 0, stream>>>(
            bl, Wedge + l * DMODEL * DM, bedge + l * DM, xs, xd, gs, gd, xij, E);
        k_logit<<<(T + 255) / 256, 256, 0, stream>>>(
            xij, packed, eids, attn + l * DM, logits, T);
        k_attend<<<(E * 16 + 255) / 256, 256, 0, stream>>>(
            xij, logits, packed, rowp, msg, E);
        k_aggregate<<<(N * 16 + 255) / 256, 256, 0, stream>>>(
            msg, erowp, eord, ft, N);
        k_ffn1<<<dim3((N + 63) / 64, HDIM / 64), 256, 0, stream>>>(
            ft, W1 + l * DM * HDIM, b1 + l * HDIM, hb, N);
        k_ffn2<<<dim3(DMODEL / 64, (N + 31) / 32), 256, 0, stream>>>(
            hb, W2 + l * HDIM * DMODEL, b2 + l * DMODEL, x, N);
    }

    // ---- output head ----
    hipMemsetAsync(accs, 0, 4, stream);
    k_out_reduce<<<120, 256, 0, stream>>>(x, Wfc, accs, N * DMODEL);
    k_out_final<<<1, 1, 0, stream>>>(accs, bfc, (float*)d_out, 1.0f / (float)N);
}

// Round 10
// 1317.210 us; speedup vs baseline: 1.2095x; 1.0926x over previous
//
#include <hip/hip_runtime.h>
#include <math.h>

// M3GNet-like GNN forward. N=10000 nodes, E=160000 edges, T=1200000 triplets,
// D=256, DM=64, H=1024, L=3, output = scalar mean energy (fp32).
//
// R9: FFN1/FFN2 on MFMA (mfma_f32_16x16x32_bf16), no LDS, no barriers.
//  - ft stored bf16 (aggregate packs), h already bf16.
//  - W1/W2 cast+transposed to bf16 [n][k] once in setup (k_castT, all layers).
//  - wave = 16x64 output tile (1 A-frag + 4 B-frags per K-step), block = 4
//    waves stacked in M. A/B frags are direct 16B global loads (L2-hot B).
//  - R8's vector-ALU ffn2 was LDS-issue bound (2x ds_read_b32 + 1x b128 per
//    8 FMA, VALUBusy capped ~33%).

#define DM 64
#define DMODEL 256
#define HDIM 1024

typedef unsigned short bf16_t;
typedef __attribute__((ext_vector_type(8))) short s8v;    // 8 bf16 (4 VGPRs)
typedef __attribute__((ext_vector_type(4))) float f4;     // MFMA acc

__device__ __forceinline__ bf16_t f2bf(float f) {
    unsigned int u = __float_as_uint(f);
    return (bf16_t)((u + 0x7FFFu + ((u >> 16) & 1u)) >> 16);   // RNE
}
__device__ __forceinline__ float bf_lo(unsigned int u) {
    return __uint_as_float(u << 16);
}
__device__ __forceinline__ float bf_hi(unsigned int u) {
    return __uint_as_float(u & 0xFFFF0000u);
}

__global__ void k_embed(const int* __restrict__ an, const float* __restrict__ emb,
                        float* __restrict__ x) {
    int n = blockIdx.x;
    int d = threadIdx.x;
    x[n * DMODEL + d] = emb[an[n] * DMODEL + d];
}

__global__ void k_edge_geom(const float* __restrict__ r, float* __restrict__ bl,
                            float* __restrict__ rn, int E) {
    int e = blockIdx.x * blockDim.x + threadIdx.x;
    if (e >= E) return;
    float a = r[e * 3 + 0], b = r[e * 3 + 1], c = r[e * 3 + 2];
    float l = sqrtf(a * a + b * b + c * c);
    bl[e] = l;
    float inv = 1.0f / l;
    rn[e * 3 + 0] = a * inv;
    rn[e * 3 + 1] = b * inv;
    rn[e * 3 + 2] = c * inv;
}

__global__ void k_hist(const int* __restrict__ idx, int* __restrict__ cnt, int M) {
    int t = blockIdx.x * blockDim.x + threadIdx.x;
    if (t < M) atomicAdd(&cnt[idx[t]], 1);
}

// ---- 3-phase exclusive scan ----
__global__ __launch_bounds__(256) void k_scan_part(
    const int* __restrict__ cnt, int* __restrict__ bsum, int M) {
    __shared__ int sm[4];
    int tid = threadIdx.x;
    int i = blockIdx.x * 256 + tid;
    int v = (i < M) ? cnt[i] : 0;
    for (int off = 32; off > 0; off >>= 1) v += __shfl_xor(v, off, 64);
    if ((tid & 63) == 0) sm[tid >> 6] = v;
    __syncthreads();
    if (tid == 0) bsum[blockIdx.x] = sm[0] + sm[1] + sm[2] + sm[3];
}

__global__ __launch_bounds__(1024) void k_scan_mid(int* __restrict__ bsum, int nb) {
    __shared__ int sm[1024];
    int tid = threadIdx.x;
    int v = (tid < nb) ? bsum[tid] : 0;
    sm[tid] = v;
    __syncthreads();
    for (int off = 1; off < 1024; off <<= 1) {
        int u = (tid >= off) ? sm[tid - off] : 0;
        __syncthreads();
        sm[tid] += u;
        __syncthreads();
    }
    if (tid < nb) bsum[tid] = sm[tid] - v;
}

__global__ __launch_bounds__(256) void k_scan_final(
    const int* __restrict__ cnt, const int* __restrict__ bsum,
    int* __restrict__ rowp, int M, int total) {
    __shared__ int sm[256];
    int tid = threadIdx.x;
    int i = blockIdx.x * 256 + tid;
    int v = (i < M) ? cnt[i] : 0;
    sm[tid] = v;
    __syncthreads();
    for (int off = 1; off < 256; off <<= 1) {
        int u = (tid >= off) ? sm[tid - off] : 0;
        __syncthreads();
        sm[tid] += u;
        __syncthreads();
    }
    if (i < M) rowp[i] = bsum[blockIdx.x] + sm[tid] - v;
    if (i == 0) rowp[M] = total;
}

__global__ void k_scatter(const int* __restrict__ ts, const int* __restrict__ td,
                          const int* __restrict__ rowp, int* __restrict__ cursor,
                          const float* __restrict__ rn,
                          int2* __restrict__ packed, int T) {
    int t = blockIdx.x * blockDim.x + threadIdx.x;
    if (t >= T) return;
    int a = ts[t], b = td[t];
    float d = rn[a * 3 + 0] * rn[b * 3 + 0]
            + rn[a * 3 + 1] * rn[b * 3 + 1]
            + rn[a * 3 + 2] * rn[b * 3 + 2];
    d = fminf(1.0f, fmaxf(-1.0f, d));
    int pos = rowp[b] + atomicAdd(&cursor[b], 1);
    packed[pos] = make_int2(a, __float_as_int(d));
}

__global__ void k_fill_eids(const int* __restrict__ rowp, int* __restrict__ eids,
                            int E) {
    int e = blockIdx.x * blockDim.x + threadIdx.x;
    if (e >= E) return;
    int beg = rowp[e], end = rowp[e + 1];
    for (int p = beg; p < end; ++p) eids[p] = e;
}

__global__ void k_escatter(const int* __restrict__ gd, const int* __restrict__ erowp,
                           int* __restrict__ cursor, int* __restrict__ eord, int E) {
    int e = blockIdx.x * blockDim.x + threadIdx.x;
    if (e >= E) return;
    int n = gd[e];
    int pos = erowp[n] + atomicAdd(&cursor[n], 1);
    eord[pos] = e;
}

// 32x32 tiled transpose + cast: src fp32 [K][Nn] -> dst bf16 [Nn][K].
__global__ __launch_bounds__(256) void k_castT(
    const float* __restrict__ src, bf16_t* __restrict__ dst, int K, int Nn) {
    __shared__ float tile[32][33];
    int k0 = blockIdx.x * 32, n0 = blockIdx.y * 32;
    int tx = threadIdx.x & 31, ty = threadIdx.x >> 5;   // ty 0..7
    #pragma unroll
    for (int i = 0; i < 4; ++i) {
        int row = ty + i * 8;
        tile[row][tx] = src[(size_t)(k0 + row) * Nn + n0 + tx];
    }
    __syncthreads();
    #pragma unroll
    for (int i = 0; i < 4; ++i) {
        int row = ty + i * 8;
        dst[(size_t)(n0 + row) * K + k0 + tx] = f2bf(tile[tx][row]);
    }
}

// xs = x@Wsrc + bsrc ; xd = x@Wdst + bdst   (wave per node, lane = dm)
__global__ __launch_bounds__(256) void k_node_proj(
    const float* __restrict__ x,
    const float* __restrict__ Ws, const float* __restrict__ bs,
    const float* __restrict__ Wd, const float* __restrict__ bd,
    float* __restrict__ xs, float* __restrict__ xd, int N) {
    int lane = threadIdx.x & 63;
    int n = blockIdx.x * 4 + (threadIdx.x >> 6);
    if (n >= N) return;
    const float* xr = x + (size_t)n * DMODEL;
    float as = 0.f, ad = 0.f;
    for (int d = 0; d < DMODEL; ++d) {
        float xv = xr[d];
        as = fmaf(xv, Ws[d * DM + lane], as);
        ad = fmaf(xv, Wd[d * DM + lane], ad);
    }
    xs[n * DM + lane] = as + bs[lane];
    xd[n * DM + lane] = ad + bd[lane];
}

// xij[e][m] = RBF(bl[e]) @ Wedge + bedge + xs[g_src[e]] + xd[g_dst[e]] (bf16 out)
__global__ __launch_bounds__(256) void k_xij(
    const float* __restrict__ bl,
    const float* __restrict__ We, const float* __restrict__ be,
    const float* __restrict__ xs, const float* __restrict__ xd,
    const int* __restrict__ gs, const int* __restrict__ gd,
    bf16_t* __restrict__ xij, int E) {
    __shared__ float A[32][68];
    __shared__ float B[32][68];
    int tid = threadIdx.x;
    int e0 = blockIdx.x * 64;
    int ty = tid >> 4, tx = tid & 15;
    int row = tid & 63;
    int kbase = tid >> 6;
    const float step = 8.0f / 255.0f;
    const float gamma = (255.0f / 8.0f) * (255.0f / 8.0f);
    int erow = e0 + row;
    float blv = (erow < E) ? bl[erow] : 0.f;
    float acc[4][4] = {};
    for (int k0 = 0; k0 < DMODEL; k0 += 32) {
        #pragma unroll
        for (int i = 0; i < 8; ++i) {
            int kk = i * 4 + kbase;
            float c = (float)(k0 + kk) * step;
            float dd = blv - c;
            A[kk][row] = __expf(-gamma * dd * dd);
            B[kk][row] = We[(size_t)(k0 + kk) * DM + row];
        }
        __syncthreads();
        for (int kk = 0; kk < 32; ++kk) {
            float4 av = *(const float4*)&A[kk][ty * 4];
            float4 bv = *(const float4*)&B[kk][tx * 4];
            float a4[4] = {av.x, av.y, av.z, av.w};
            float b4[4] = {bv.x, bv.y, bv.z, bv.w};
            for (int i = 0; i < 4; ++i)
                for (int j = 0; j < 4; ++j)
                    acc[i][j] = fmaf(a4[i], b4[j], acc[i][j]);
        }
        __syncthreads();
    }
    int m0 = tx * 4;
    float4 bev = *(const float4*)&be[m0];
    for (int i = 0; i < 4; ++i) {
        int e = e0 + ty * 4 + i;
        if (e >= E) continue;
        int s = gs[e], d2 = gd[e];
        float4 xsv = *(const float4*)&xs[(size_t)s * DM + m0];
        float4 xdv = *(const float4*)&xd[(size_t)d2 * DM + m0];
        ushort4 o;
        o.x = f2bf(acc[i][0] + xsv.x + xdv.x + bev.x);
        o.y = f2bf(acc[i][1] + xsv.y + xdv.y + bev.y);
        o.z = f2bf(acc[i][2] + xsv.z + xdv.z + bev.z);
        o.w = f2bf(acc[i][3] + xsv.w + xdv.w + bev.w);
        *(ushort4*)&xij[(size_t)e * DM + m0] = o;
    }
}

// thread per triplet: Chebyshev + silu dot; bf16 row gathers.
__global__ __launch_bounds__(256) void k_logit(
    const bf16_t* __restrict__ xij, const int2* __restrict__ packed,
    const int* __restrict__ eids,
    const float* __restrict__ attn_l, float* __restrict__ logits, int T) {
    int p = blockIdx.x * 256 + threadIdx.x;
    if (p >= T) return;
    int2 pk = packed[p];
    int s = pk.x;
    float c = __int_as_float(pk.y);
    int e = eids[p];
    float c2 = 2.0f * c;
    const uint4* xsr = (const uint4*)(xij + (size_t)s * DM);
    const uint4* xer = (const uint4*)(xij + (size_t)e * DM);
    float t0 = 1.0f, t1 = c;
    float acc = 0.f;
    #pragma unroll
    for (int j = 0; j < 8; ++j) {
        uint4 a4 = xsr[j];
        uint4 b4 = xer[j];
        unsigned int au[4] = {a4.x, a4.y, a4.z, a4.w};
        unsigned int bu[4] = {b4.x, b4.y, b4.z, b4.w};
        #pragma unroll
        for (int q = 0; q < 4; ++q) {
            float us[2] = {bf_lo(au[q]) + bf_lo(bu[q]),
                           bf_hi(au[q]) + bf_hi(bu[q])};
            #pragma unroll
            for (int m = 0; m < 2; ++m) {
                int k = j * 8 + q * 2 + m;
                float tk;
                if (k == 0)      tk = 1.0f;
                else if (k == 1) tk = c;
                else { tk = fmaf(c2, t1, -t0); t0 = t1; t1 = tk; }
                float v = tk + us[m];
                float sl = v / (1.0f + __expf(-v));
                acc = fmaf(sl, attn_l[k], acc);
            }
        }
    }
    logits[p] = acc;
}

// thread per (edge, channel-quad): softmax + weighted bf16 gather; bf16 store.
__global__ __launch_bounds__(256) void k_attend(
    const bf16_t* __restrict__ xij, const float* __restrict__ logits,
    const int2* __restrict__ packed, const int* __restrict__ rowp,
    bf16_t* __restrict__ msg, int E) {
    int gtid = blockIdx.x * 256 + threadIdx.x;
    int e = gtid >> 4;
    if (e >= E) return;
    int quad = gtid & 15;
    int beg = rowp[e], end = rowp[e + 1];
    float a0 = 0.f, a1 = 0.f, a2 = 0.f, a3 = 0.f;
    if (beg < end) {
        float lm = -1e30f;
        for (int p = beg; p < end; ++p) lm = fmaxf(lm, logits[p]);
        float den = 0.f;
        for (int p = beg; p < end; ++p) {
            float w = __expf(logits[p] - lm);
            den += w;
            int s = packed[p].x;
            uint2 uv = *(const uint2*)&xij[(size_t)s * DM + quad * 4];
            a0 = fmaf(w, bf_lo(uv.x), a0);
            a1 = fmaf(w, bf_hi(uv.x), a1);
            a2 = fmaf(w, bf_lo(uv.y), a2);
            a3 = fmaf(w, bf_hi(uv.y), a3);
        }
        float inv = 1.0f / den;
        a0 *= inv; a1 *= inv; a2 *= inv; a3 *= inv;
    }
    ushort4 o = {f2bf(a0), f2bf(a1), f2bf(a2), f2bf(a3)};
    *(ushort4*)&msg[(size_t)e * DM + quad * 4] = o;
}

// thread per (node, channel-quad): sum bf16 msg -> bf16 ft.
__global__ __launch_bounds__(256) void k_aggregate(
    const bf16_t* __restrict__ msg, const int* __restrict__ erowp,
    const int* __restrict__ eord, bf16_t* __restrict__ ft, int N) {
    int gtid = blockIdx.x * 256 + threadIdx.x;
    int n = gtid >> 4;
    if (n >= N) return;
    int quad = gtid & 15;
    int beg = erowp[n], end = erowp[n + 1];
    float a0 = 0.f, a1 = 0.f, a2 = 0.f, a3 = 0.f;
    for (int j = beg; j < end; ++j) {
        uint2 uv = *(const uint2*)&msg[(size_t)eord[j] * DM + quad * 4];
        a0 += bf_lo(uv.x); a1 += bf_hi(uv.x);
        a2 += bf_lo(uv.y); a3 += bf_hi(uv.y);
    }
    ushort4 o = {f2bf(a0), f2bf(a1), f2bf(a2), f2bf(a3)};
    *(ushort4*)&ft[(size_t)n * DM + quad * 4] = o;
}

// MFMA ffn1: h = silu(ft(bf16) @ W1 + b1), h bf16.
// wave = 16x64 tile (1 A-frag, 4 B-frags / K-step), block = 4 waves in M.
// grid (ceil(N/64)=157, HDIM/64=16); no LDS, no barriers.
__global__ __launch_bounds__(256) void k_ffn1(
    const bf16_t* __restrict__ ft, const bf16_t* __restrict__ W1t,
    const float* __restrict__ b1, bf16_t* __restrict__ h, int N) {
    int tid = threadIdx.x;
    int w = tid >> 6, lane = tid & 63;
    int col = lane & 15, quad = lane >> 4;
    int m0 = blockIdx.x * 64 + w * 16;
    int c0 = blockIdx.y * 64;
    f4 acc[4] = {{0.f,0.f,0.f,0.f},{0.f,0.f,0.f,0.f},
                 {0.f,0.f,0.f,0.f},{0.f,0.f,0.f,0.f}};
    #pragma unroll
    for (int k0 = 0; k0 < DM; k0 += 32) {
        s8v a = *(const s8v*)&ft[(size_t)(m0 + col) * DM + k0 + quad * 8];
        #pragma unroll
        for (int t = 0; t < 4; ++t) {
            s8v b = *(const s8v*)&W1t[(size_t)(c0 + t * 16 + col) * DM + k0 + quad * 8];
            acc[t] = __builtin_amdgcn_mfma_f32_16x16x32_bf16(a, b, acc[t], 0, 0, 0);
        }
    }
    #pragma unroll
    for (int t = 0; t < 4; ++t) {
        int c = c0 + t * 16 + col;
        float bb = b1[c];
        #pragma unroll
        for (int r = 0; r < 4; ++r) {
            int m = m0 + quad * 4 + r;
            if (m < N) {
                float v = acc[t][r] + bb;
                h[(size_t)m * HDIM + c] = f2bf(v / (1.0f + __expf(-v)));
            }
        }
    }
}

// MFMA ffn2: x = h(bf16) @ W2 + b2 (fp32 out). grid (157, DMODEL/64=4).
__global__ __launch_bounds__(256) void k_ffn2(
    const bf16_t* __restrict__ h, const bf16_t* __restrict__ W2t,
    const float* __restrict__ b2, float* __restrict__ x, int N) {
    int tid = threadIdx.x;
    int w = tid >> 6, lane = tid & 63;
    int col = lane & 15, quad = lane >> 4;
    int m0 = blockIdx.x * 64 + w * 16;
    int c0 = blockIdx.y * 64;
    f4 acc[4] = {{0.f,0.f,0.f,0.f},{0.f,0.f,0.f,0.f},
                 {0.f,0.f,0.f,0.f},{0.f,0.f,0.f,0.f}};
    for (int k0 = 0; k0 < HDIM; k0 += 32) {
        s8v a = *(const s8v*)&h[(size_t)(m0 + col) * HDIM + k0 + quad * 8];
        #pragma unroll
        for (int t = 0; t < 4; ++t) {
            s8v b = *(const s8v*)&W2t[(size_t)(c0 + t * 16 + col) * HDIM + k0 + quad * 8];
            acc[t] = __builtin_amdgcn_mfma_f32_16x16x32_bf16(a, b, acc[t], 0, 0, 0);
        }
    }
    #pragma unroll
    for (int t = 0; t < 4; ++t) {
        int c = c0 + t * 16 + col;
        float bb = b2[c];
        #pragma unroll
        for (int r = 0; r < 4; ++r) {
            int m = m0 + quad * 4 + r;
            if (m < N) x[(size_t)m * DMODEL + c] = acc[t][r] + bb;
        }
    }
}

// grid-stride dot(x, tiled Wfc), one atomic per block.
__global__ __launch_bounds__(256) void k_out_reduce(
    const float* __restrict__ x, const float* __restrict__ Wfc,
    float* __restrict__ acc, int NT) {
    __shared__ float sm[4];
    int tid = threadIdx.x;
    float v = 0.f;
    for (int i = blockIdx.x * blockDim.x + tid; i < NT; i += gridDim.x * blockDim.x)
        v = fmaf(x[i], Wfc[i & (DMODEL - 1)], v);
    for (int off = 32; off > 0; off >>= 1) v += __shfl_xor(v, off, 64);
    if ((tid & 63) == 0) sm[tid >> 6] = v;
    __syncthreads();
    if (tid == 0) {
        float s = sm[0] + sm[1] + sm[2] + sm[3];
        atomicAdd(acc, s);
    }
}

__global__ void k_out_final(const float* __restrict__ acc, const float* __restrict__ bfc,
                            float* __restrict__ out, float invN) {
    out[0] = acc[0] * invN + bfc[0];
}

extern "C" void kernel_launch(void* const* d_in, const int* in_sizes, int n_in,
                              void* d_out, int out_size, void* d_ws, size_t ws_size,
                              hipStream_t stream) {
    const int*   an    = (const int*)d_in[0];
    const int*   gs    = (const int*)d_in[1];
    const int*   gd    = (const int*)d_in[2];
    const int*   ts    = (const int*)d_in[3];
    const int*   td    = (const int*)d_in[4];
    const float* r     = (const float*)d_in[5];
    const float* emb   = (const float*)d_in[6];
    const float* Wsrc  = (const float*)d_in[7];
    const float* bsrc  = (const float*)d_in[8];
    const float* Wdst  = (const float*)d_in[9];
    const float* bdst  = (const float*)d_in[10];
    const float* Wedge = (const float*)d_in[11];
    const float* bedge = (const float*)d_in[12];
    const float* attn  = (const float*)d_in[13];
    const float* W1    = (const float*)d_in[14];
    const float* b1    = (const float*)d_in[15];
    const float* W2    = (const float*)d_in[16];
    const float* b2    = (const float*)d_in[17];
    const float* Wfc   = (const float*)d_in[18];
    const float* bfc   = (const float*)d_in[19];

    const int N = in_sizes[0];
    const int E = in_sizes[1];
    const int T = in_sizes[3];

    char* w = (char*)d_ws;
    size_t off = 0;
    auto alloc = [&](size_t bytes) {
        void* p = w + off;
        off += (bytes + 255) & ~(size_t)255;
        return p;
    };
    float*  x      = (float*) alloc((size_t)N * DMODEL * 4);
    float*  rn     = (float*) alloc((size_t)E * 3 * 4);
    float*  bl     = (float*) alloc((size_t)E * 4);
    int*    cnt    = (int*)   alloc((size_t)E * 4);
    int*    rowp   = (int*)   alloc(((size_t)E + 1) * 4);
    int*    bsum   = (int*)   alloc(4096);
    int2*   packed = (int2*)  alloc((size_t)T * 8);
    int*    eids   = (int*)   alloc((size_t)T * 4);
    float*  logits = (float*) alloc((size_t)T * 4);
    int*    ecnt   = (int*)   alloc((size_t)N * 4);
    int*    erowp  = (int*)   alloc(((size_t)N + 1) * 4);
    int*    eord   = (int*)   alloc((size_t)E * 4);
    float*  xs     = (float*) alloc((size_t)N * DM * 4);
    float*  xd     = (float*) alloc((size_t)N * DM * 4);
    bf16_t* xij    = (bf16_t*)alloc((size_t)E * DM * 2);
    bf16_t* msg    = (bf16_t*)alloc((size_t)E * DM * 2);
    bf16_t* ft     = (bf16_t*)alloc((size_t)(N + 64) * DM * 2);     // padded rows
    bf16_t* hb     = (bf16_t*)alloc((size_t)(N + 64) * HDIM * 2);   // padded rows
    bf16_t* W1t    = (bf16_t*)alloc((size_t)3 * HDIM * DM * 2);
    bf16_t* W2t    = (bf16_t*)alloc((size_t)3 * DMODEL * HDIM * 2);
    float*  accs   = (float*) alloc(64);
    (void)ws_size; (void)n_in; (void)out_size;

    const int nbScanE = (E + 255) / 256;
    const int nbScanN = (N + 255) / 256;

    // ---- setup (layer-invariant) ----
    k_embed<<<N, 256, 0, stream>>>(an, emb, x);
    k_edge_geom<<<(E + 255) / 256, 256, 0, stream>>>(r, bl, rn, E);
    // weight transposes/casts for MFMA FFNs (all layers)
    for (int l = 0; l < 3; ++l) {
        k_castT<<<dim3(DM / 32, HDIM / 32), 256, 0, stream>>>(
            W1 + (size_t)l * DM * HDIM, W1t + (size_t)l * HDIM * DM, DM, HDIM);
        k_castT<<<dim3(HDIM / 32, DMODEL / 32), 256, 0, stream>>>(
            W2 + (size_t)l * HDIM * DMODEL, W2t + (size_t)l * DMODEL * HDIM,
            HDIM, DMODEL);
    }
    // triplet CSR by t_dst
    hipMemsetAsync(cnt, 0, (size_t)E * 4, stream);
    k_hist<<<(T + 255) / 256, 256, 0, stream>>>(td, cnt, T);
    k_scan_part<<<nbScanE, 256, 0, stream>>>(cnt, bsum, E);
    k_scan_mid<<<1, 1024, 0, stream>>>(bsum, nbScanE);
    k_scan_final<<<nbScanE, 256, 0, stream>>>(cnt, bsum, rowp, E, T);
    hipMemsetAsync(cnt, 0, (size_t)E * 4, stream);
    k_scatter<<<(T + 255) / 256, 256, 0, stream>>>(ts, td, rowp, cnt, rn,
                                                   packed, T);
    k_fill_eids<<<(E + 255) / 256, 256, 0, stream>>>(rowp, eids, E);
    // edge CSR by gd
    hipMemsetAsync(ecnt, 0, (size_t)N * 4, stream);
    k_hist<<<(E + 255) / 256, 256, 0, stream>>>(gd, ecnt, E);
    k_scan_part<<<nbScanN, 256, 0, stream>>>(ecnt, bsum, N);
    k_scan_mid<<<1, 1024, 0, stream>>>(bsum, nbScanN);
    k_scan_final<<<nbScanN, 256, 0, stream>>>(ecnt, bsum, erowp, N, E);
    hipMemsetAsync(ecnt, 0, (size_t)N * 4, stream);
    k_escatter<<<(E + 255) / 256, 256, 0, stream>>>(gd, erowp, ecnt, eord, E);

    // ---- layers ----
    for (int l = 0; l < 3; ++l) {
        k_node_proj<<<(N + 3) / 4, 256, 0, stream>>>(
            x, Wsrc + l * DMODEL * DM, bsrc + l * DM,
            Wdst + l * DMODEL * DM, bdst + l * DM, xs, xd, N);
        k_xij<<<(E + 63) / 64, 256, 0, stream>>>(
            bl, Wedge + l * DMODEL * DM, bedge + l * DM, xs, xd, gs, gd, xij, E);
        k_logit<<<(T + 255) / 256, 256, 0, stream>>>(
            xij, packed, eids, attn + l * DM, logits, T);
        k_attend<<<(E * 16 + 255) / 256, 256, 0, stream>>>(
            xij, logits, packed, rowp, msg, E);
        k_aggregate<<<(N * 16 + 255) / 256, 256, 0, stream>>>(
            msg, erowp, eord, ft, N);
        k_ffn1<<<dim3((N + 63) / 64, HDIM / 64), 256, 0, stream>>>(
            ft, W1t + (size_t)l * HDIM * DM, b1 + l * HDIM, hb, N);
        k_ffn2<<<dim3((N + 63) / 64, DMODEL / 64), 256, 0, stream>>>(
            hb, W2t + (size_t)l * DMODEL * HDIM, b2 + l * DMODEL, x, N);
    }

    // ---- output head ----
    hipMemsetAsync(accs, 0, 4, stream);
    k_out_reduce<<<120, 256, 0, stream>>>(x, Wfc, accs, N * DMODEL);
    k_out_final<<<1, 1, 0, stream>>>(accs, bfc, (float*)d_out, 1.0f / (float)N);
}

// Round 11
// 1260.701 us; speedup vs baseline: 1.2637x; 1.0448x over previous
//
#include <hip/hip_runtime.h>
#include <math.h>

// M3GNet-like GNN forward. N=10000 nodes, E=160000 edges, T=1200000 triplets,
// D=256, DM=64, H=1024, L=3, output = scalar mean energy (fp32).
//
// R10: k_xij moved to MFMA. R9's vector-ALU k_xij was VALU-bound (68% busy,
// 4096 FMA-inst/thread). Now: A-fragments = RBF computed on the fly into bf16
// registers (8 expf/K-step/lane), B = Wedge^T bf16 (cast once in setup,
// 32 KB L2-hot), 32 MFMA/wave, fused gather-add epilogue. No LDS/barriers.

#define DM 64
#define DMODEL 256
#define HDIM 1024

typedef unsigned short bf16_t;
typedef __attribute__((ext_vector_type(8))) short s8v;    // 8 bf16 (4 VGPRs)
typedef __attribute__((ext_vector_type(4))) float f4;     // MFMA acc

__device__ __forceinline__ bf16_t f2bf(float f) {
    unsigned int u = __float_as_uint(f);
    return (bf16_t)((u + 0x7FFFu + ((u >> 16) & 1u)) >> 16);   // RNE
}
__device__ __forceinline__ float bf_lo(unsigned int u) {
    return __uint_as_float(u << 16);
}
__device__ __forceinline__ float bf_hi(unsigned int u) {
    return __uint_as_float(u & 0xFFFF0000u);
}

__global__ void k_embed(const int* __restrict__ an, const float* __restrict__ emb,
                        float* __restrict__ x) {
    int n = blockIdx.x;
    int d = threadIdx.x;
    x[n * DMODEL + d] = emb[an[n] * DMODEL + d];
}

__global__ void k_edge_geom(const float* __restrict__ r, float* __restrict__ bl,
                            float* __restrict__ rn, int E) {
    int e = blockIdx.x * blockDim.x + threadIdx.x;
    if (e >= E) return;
    float a = r[e * 3 + 0], b = r[e * 3 + 1], c = r[e * 3 + 2];
    float l = sqrtf(a * a + b * b + c * c);
    bl[e] = l;
    float inv = 1.0f / l;
    rn[e * 3 + 0] = a * inv;
    rn[e * 3 + 1] = b * inv;
    rn[e * 3 + 2] = c * inv;
}

__global__ void k_hist(const int* __restrict__ idx, int* __restrict__ cnt, int M) {
    int t = blockIdx.x * blockDim.x + threadIdx.x;
    if (t < M) atomicAdd(&cnt[idx[t]], 1);
}

// ---- 3-phase exclusive scan ----
__global__ __launch_bounds__(256) void k_scan_part(
    const int* __restrict__ cnt, int* __restrict__ bsum, int M) {
    __shared__ int sm[4];
    int tid = threadIdx.x;
    int i = blockIdx.x * 256 + tid;
    int v = (i < M) ? cnt[i] : 0;
    for (int off = 32; off > 0; off >>= 1) v += __shfl_xor(v, off, 64);
    if ((tid & 63) == 0) sm[tid >> 6] = v;
    __syncthreads();
    if (tid == 0) bsum[blockIdx.x] = sm[0] + sm[1] + sm[2] + sm[3];
}

__global__ __launch_bounds__(1024) void k_scan_mid(int* __restrict__ bsum, int nb) {
    __shared__ int sm[1024];
    int tid = threadIdx.x;
    int v = (tid < nb) ? bsum[tid] : 0;
    sm[tid] = v;
    __syncthreads();
    for (int off = 1; off < 1024; off <<= 1) {
        int u = (tid >= off) ? sm[tid - off] : 0;
        __syncthreads();
        sm[tid] += u;
        __syncthreads();
    }
    if (tid < nb) bsum[tid] = sm[tid] - v;
}

__global__ __launch_bounds__(256) void k_scan_final(
    const int* __restrict__ cnt, const int* __restrict__ bsum,
    int* __restrict__ rowp, int M, int total) {
    __shared__ int sm[256];
    int tid = threadIdx.x;
    int i = blockIdx.x * 256 + tid;
    int v = (i < M) ? cnt[i] : 0;
    sm[tid] = v;
    __syncthreads();
    for (int off = 1; off < 256; off <<= 1) {
        int u = (tid >= off) ? sm[tid - off] : 0;
        __syncthreads();
        sm[tid] += u;
        __syncthreads();
    }
    if (i < M) rowp[i] = bsum[blockIdx.x] + sm[tid] - v;
    if (i == 0) rowp[M] = total;
}

__global__ void k_scatter(const int* __restrict__ ts, const int* __restrict__ td,
                          const int* __restrict__ rowp, int* __restrict__ cursor,
                          const float* __restrict__ rn,
                          int2* __restrict__ packed, int T) {
    int t = blockIdx.x * blockDim.x + threadIdx.x;
    if (t >= T) return;
    int a = ts[t], b = td[t];
    float d = rn[a * 3 + 0] * rn[b * 3 + 0]
            + rn[a * 3 + 1] * rn[b * 3 + 1]
            + rn[a * 3 + 2] * rn[b * 3 + 2];
    d = fminf(1.0f, fmaxf(-1.0f, d));
    int pos = rowp[b] + atomicAdd(&cursor[b], 1);
    packed[pos] = make_int2(a, __float_as_int(d));
}

__global__ void k_fill_eids(const int* __restrict__ rowp, int* __restrict__ eids,
                            int E) {
    int e = blockIdx.x * blockDim.x + threadIdx.x;
    if (e >= E) return;
    int beg = rowp[e], end = rowp[e + 1];
    for (int p = beg; p < end; ++p) eids[p] = e;
}

__global__ void k_escatter(const int* __restrict__ gd, const int* __restrict__ erowp,
                           int* __restrict__ cursor, int* __restrict__ eord, int E) {
    int e = blockIdx.x * blockDim.x + threadIdx.x;
    if (e >= E) return;
    int n = gd[e];
    int pos = erowp[n] + atomicAdd(&cursor[n], 1);
    eord[pos] = e;
}

// 32x32 tiled transpose + cast: src fp32 [K][Nn] -> dst bf16 [Nn][K].
__global__ __launch_bounds__(256) void k_castT(
    const float* __restrict__ src, bf16_t* __restrict__ dst, int K, int Nn) {
    __shared__ float tile[32][33];
    int k0 = blockIdx.x * 32, n0 = blockIdx.y * 32;
    int tx = threadIdx.x & 31, ty = threadIdx.x >> 5;
    #pragma unroll
    for (int i = 0; i < 4; ++i) {
        int row = ty + i * 8;
        tile[row][tx] = src[(size_t)(k0 + row) * Nn + n0 + tx];
    }
    __syncthreads();
    #pragma unroll
    for (int i = 0; i < 4; ++i) {
        int row = ty + i * 8;
        dst[(size_t)(n0 + row) * K + k0 + tx] = f2bf(tile[tx][row]);
    }
}

// xs = x@Wsrc + bsrc ; xd = x@Wdst + bdst   (wave per node, lane = dm)
__global__ __launch_bounds__(256) void k_node_proj(
    const float* __restrict__ x,
    const float* __restrict__ Ws, const float* __restrict__ bs,
    const float* __restrict__ Wd, const float* __restrict__ bd,
    float* __restrict__ xs, float* __restrict__ xd, int N) {
    int lane = threadIdx.x & 63;
    int n = blockIdx.x * 4 + (threadIdx.x >> 6);
    if (n >= N) return;
    const float* xr = x + (size_t)n * DMODEL;
    float as = 0.f, ad = 0.f;
    for (int d = 0; d < DMODEL; ++d) {
        float xv = xr[d];
        as = fmaf(xv, Ws[d * DM + lane], as);
        ad = fmaf(xv, Wd[d * DM + lane], ad);
    }
    xs[n * DM + lane] = as + bs[lane];
    xd[n * DM + lane] = ad + bd[lane];
}

// MFMA k_xij: xij[e][c] = (RBF(bl[e]) @ Wedge)[c] + xs[gs[e]][c] + xd[gd[e]][c] + be[c]
// wave = 16 edges x 64 cols; A = on-the-fly RBF bf16; B = Wedgt bf16 [c][k].
// grid ceil(E/64) = 2500 blocks x 4 waves. No LDS, no barriers.
__global__ __launch_bounds__(256) void k_xij(
    const float* __restrict__ bl, const bf16_t* __restrict__ Wedgt,
    const float* __restrict__ be,
    const float* __restrict__ xs, const float* __restrict__ xd,
    const int* __restrict__ gs, const int* __restrict__ gd,
    bf16_t* __restrict__ xij, int E) {
    int tid = threadIdx.x;
    int w = tid >> 6, lane = tid & 63;
    int col = lane & 15, quad = lane >> 4;
    int m0 = blockIdx.x * 64 + w * 16;       // this wave's first edge
    const float step = 8.0f / 255.0f;
    const float gamma = (255.0f / 8.0f) * (255.0f / 8.0f);
    int me = m0 + col;
    float blv = (me < E) ? bl[me] : 0.f;     // A-row edge for this lane
    f4 acc[4] = {{0.f,0.f,0.f,0.f},{0.f,0.f,0.f,0.f},
                 {0.f,0.f,0.f,0.f},{0.f,0.f,0.f,0.f}};
    #pragma unroll
    for (int k0 = 0; k0 < DMODEL; k0 += 32) {
        // A-fragment: RBF(blv, k) for k = k0 + quad*8 + j
        s8v a;
        #pragma unroll
        for (int j = 0; j < 8; ++j) {
            float c = (float)(k0 + quad * 8 + j) * step;
            float dd = blv - c;
            a[j] = (short)f2bf(__expf(-gamma * dd * dd));
        }
        #pragma unroll
        for (int t = 0; t < 4; ++t) {
            s8v b = *(const s8v*)&Wedgt[(size_t)(t * 16 + col) * DMODEL + k0 + quad * 8];
            acc[t] = __builtin_amdgcn_mfma_f32_16x16x32_bf16(a, b, acc[t], 0, 0, 0);
        }
    }
    // epilogue: C layout row = quad*4+r (edge), col = t*16 + col (channel)
    #pragma unroll
    for (int r = 0; r < 4; ++r) {
        int e = m0 + quad * 4 + r;
        if (e >= E) continue;
        int s = gs[e], d2 = gd[e];
        #pragma unroll
        for (int t = 0; t < 4; ++t) {
            int c = t * 16 + col;
            float v = acc[t][r] + xs[(size_t)s * DM + c] + xd[(size_t)d2 * DM + c] + be[c];
            xij[(size_t)e * DM + c] = f2bf(v);
        }
    }
}

// thread per triplet: Chebyshev + silu dot; bf16 row gathers.
__global__ __launch_bounds__(256) void k_logit(
    const bf16_t* __restrict__ xij, const int2* __restrict__ packed,
    const int* __restrict__ eids,
    const float* __restrict__ attn_l, float* __restrict__ logits, int T) {
    int p = blockIdx.x * 256 + threadIdx.x;
    if (p >= T) return;
    int2 pk = packed[p];
    int s = pk.x;
    float c = __int_as_float(pk.y);
    int e = eids[p];
    float c2 = 2.0f * c;
    const uint4* xsr = (const uint4*)(xij + (size_t)s * DM);
    const uint4* xer = (const uint4*)(xij + (size_t)e * DM);
    float t0 = 1.0f, t1 = c;
    float acc = 0.f;
    #pragma unroll
    for (int j = 0; j < 8; ++j) {
        uint4 a4 = xsr[j];
        uint4 b4 = xer[j];
        unsigned int au[4] = {a4.x, a4.y, a4.z, a4.w};
        unsigned int bu[4] = {b4.x, b4.y, b4.z, b4.w};
        #pragma unroll
        for (int q = 0; q < 4; ++q) {
            float us[2] = {bf_lo(au[q]) + bf_lo(bu[q]),
                           bf_hi(au[q]) + bf_hi(bu[q])};
            #pragma unroll
            for (int m = 0; m < 2; ++m) {
                int k = j * 8 + q * 2 + m;
                float tk;
                if (k == 0)      tk = 1.0f;
                else if (k == 1) tk = c;
                else { tk = fmaf(c2, t1, -t0); t0 = t1; t1 = tk; }
                float v = tk + us[m];
                float sl = v / (1.0f + __expf(-v));
                acc = fmaf(sl, attn_l[k], acc);
            }
        }
    }
    logits[p] = acc;
}

// thread per (edge, channel-quad): softmax + weighted bf16 gather; bf16 store.
__global__ __launch_bounds__(256) void k_attend(
    const bf16_t* __restrict__ xij, const float* __restrict__ logits,
    const int2* __restrict__ packed, const int* __restrict__ rowp,
    bf16_t* __restrict__ msg, int E) {
    int gtid = blockIdx.x * 256 + threadIdx.x;
    int e = gtid >> 4;
    if (e >= E) return;
    int quad = gtid & 15;
    int beg = rowp[e], end = rowp[e + 1];
    float a0 = 0.f, a1 = 0.f, a2 = 0.f, a3 = 0.f;
    if (beg < end) {
        float lm = -1e30f;
        for (int p = beg; p < end; ++p) lm = fmaxf(lm, logits[p]);
        float den = 0.f;
        for (int p = beg; p < end; ++p) {
            float w = __expf(logits[p] - lm);
            den += w;
            int s = packed[p].x;
            uint2 uv = *(const uint2*)&xij[(size_t)s * DM + quad * 4];
            a0 = fmaf(w, bf_lo(uv.x), a0);
            a1 = fmaf(w, bf_hi(uv.x), a1);
            a2 = fmaf(w, bf_lo(uv.y), a2);
            a3 = fmaf(w, bf_hi(uv.y), a3);
        }
        float inv = 1.0f / den;
        a0 *= inv; a1 *= inv; a2 *= inv; a3 *= inv;
    }
    ushort4 o = {f2bf(a0), f2bf(a1), f2bf(a2), f2bf(a3)};
    *(ushort4*)&msg[(size_t)e * DM + quad * 4] = o;
}

// thread per (node, channel-quad): sum bf16 msg -> bf16 ft.
__global__ __launch_bounds__(256) void k_aggregate(
    const bf16_t* __restrict__ msg, const int* __restrict__ erowp,
    const int* __restrict__ eord, bf16_t* __restrict__ ft, int N) {
    int gtid = blockIdx.x * 256 + threadIdx.x;
    int n = gtid >> 4;
    if (n >= N) return;
    int quad = gtid & 15;
    int beg = erowp[n], end = erowp[n + 1];
    float a0 = 0.f, a1 = 0.f, a2 = 0.f, a3 = 0.f;
    for (int j = beg; j < end; ++j) {
        uint2 uv = *(const uint2*)&msg[(size_t)eord[j] * DM + quad * 4];
        a0 += bf_lo(uv.x); a1 += bf_hi(uv.x);
        a2 += bf_lo(uv.y); a3 += bf_hi(uv.y);
    }
    ushort4 o = {f2bf(a0), f2bf(a1), f2bf(a2), f2bf(a3)};
    *(ushort4*)&ft[(size_t)n * DM + quad * 4] = o;
}

// MFMA ffn1: h = silu(ft(bf16) @ W1 + b1), h bf16. grid (157, 16).
__global__ __launch_bounds__(256) void k_ffn1(
    const bf16_t* __restrict__ ft, const bf16_t* __restrict__ W1t,
    const float* __restrict__ b1, bf16_t* __restrict__ h, int N) {
    int tid = threadIdx.x;
    int w = tid >> 6, lane = tid & 63;
    int col = lane & 15, quad = lane >> 4;
    int m0 = blockIdx.x * 64 + w * 16;
    int c0 = blockIdx.y * 64;
    f4 acc[4] = {{0.f,0.f,0.f,0.f},{0.f,0.f,0.f,0.f},
                 {0.f,0.f,0.f,0.f},{0.f,0.f,0.f,0.f}};
    #pragma unroll
    for (int k0 = 0; k0 < DM; k0 += 32) {
        s8v a = *(const s8v*)&ft[(size_t)(m0 + col) * DM + k0 + quad * 8];
        #pragma unroll
        for (int t = 0; t < 4; ++t) {
            s8v b = *(const s8v*)&W1t[(size_t)(c0 + t * 16 + col) * DM + k0 + quad * 8];
            acc[t] = __builtin_amdgcn_mfma_f32_16x16x32_bf16(a, b, acc[t], 0, 0, 0);
        }
    }
    #pragma unroll
    for (int t = 0; t < 4; ++t) {
        int c = c0 + t * 16 + col;
        float bb = b1[c];
        #pragma unroll
        for (int r = 0; r < 4; ++r) {
            int m = m0 + quad * 4 + r;
            if (m < N) {
                float v = acc[t][r] + bb;
                h[(size_t)m * HDIM + c] = f2bf(v / (1.0f + __expf(-v)));
            }
        }
    }
}

// MFMA ffn2: x = h(bf16) @ W2 + b2 (fp32 out). grid (157, 4).
__global__ __launch_bounds__(256) void k_ffn2(
    const bf16_t* __restrict__ h, const bf16_t* __restrict__ W2t,
    const float* __restrict__ b2, float* __restrict__ x, int N) {
    int tid = threadIdx.x;
    int w = tid >> 6, lane = tid & 63;
    int col = lane & 15, quad = lane >> 4;
    int m0 = blockIdx.x * 64 + w * 16;
    int c0 = blockIdx.y * 64;
    f4 acc[4] = {{0.f,0.f,0.f,0.f},{0.f,0.f,0.f,0.f},
                 {0.f,0.f,0.f,0.f},{0.f,0.f,0.f,0.f}};
    for (int k0 = 0; k0 < HDIM; k0 += 32) {
        s8v a = *(const s8v*)&h[(size_t)(m0 + col) * HDIM + k0 + quad * 8];
        #pragma unroll
        for (int t = 0; t < 4; ++t) {
            s8v b = *(const s8v*)&W2t[(size_t)(c0 + t * 16 + col) * HDIM + k0 + quad * 8];
            acc[t] = __builtin_amdgcn_mfma_f32_16x16x32_bf16(a, b, acc[t], 0, 0, 0);
        }
    }
    #pragma unroll
    for (int t = 0; t < 4; ++t) {
        int c = c0 + t * 16 + col;
        float bb = b2[c];
        #pragma unroll
        for (int r = 0; r < 4; ++r) {
            int m = m0 + quad * 4 + r;
            if (m < N) x[(size_t)m * DMODEL + c] = acc[t][r] + bb;
        }
    }
}

// grid-stride dot(x, tiled Wfc), one atomic per block.
__global__ __launch_bounds__(256) void k_out_reduce(
    const float* __restrict__ x, const float* __restrict__ Wfc,
    float* __restrict__ acc, int NT) {
    __shared__ float sm[4];
    int tid = threadIdx.x;
    float v = 0.f;
    for (int i = blockIdx.x * blockDim.x + tid; i < NT; i += gridDim.x * blockDim.x)
        v = fmaf(x[i], Wfc[i & (DMODEL - 1)], v);
    for (int off = 32; off > 0; off >>= 1) v += __shfl_xor(v, off, 64);
    if ((tid & 63) == 0) sm[tid >> 6] = v;
    __syncthreads();
    if (tid == 0) {
        float s = sm[0] + sm[1] + sm[2] + sm[3];
        atomicAdd(acc, s);
    }
}

__global__ void k_out_final(const float* __restrict__ acc, const float* __restrict__ bfc,
                            float* __restrict__ out, float invN) {
    out[0] = acc[0] * invN + bfc[0];
}

extern "C" void kernel_launch(void* const* d_in, const int* in_sizes, int n_in,
                              void* d_out, int out_size, void* d_ws, size_t ws_size,
                              hipStream_t stream) {
    const int*   an    = (const int*)d_in[0];
    const int*   gs    = (const int*)d_in[1];
    const int*   gd    = (const int*)d_in[2];
    const int*   ts    = (const int*)d_in[3];
    const int*   td    = (const int*)d_in[4];
    const float* r     = (const float*)d_in[5];
    const float* emb   = (const float*)d_in[6];
    const float* Wsrc  = (const float*)d_in[7];
    const float* bsrc  = (const float*)d_in[8];
    const float* Wdst  = (const float*)d_in[9];
    const float* bdst  = (const float*)d_in[10];
    const float* Wedge = (const float*)d_in[11];
    const float* bedge = (const float*)d_in[12];
    const float* attn  = (const float*)d_in[13];
    const float* W1    = (const float*)d_in[14];
    const float* b1    = (const float*)d_in[15];
    const float* W2    = (const float*)d_in[16];
    const float* b2    = (const float*)d_in[17];
    const float* Wfc   = (const float*)d_in[18];
    const float* bfc   = (const float*)d_in[19];

    const int N = in_sizes[0];
    const int E = in_sizes[1];
    const int T = in_sizes[3];

    char* w = (char*)d_ws;
    size_t off = 0;
    auto alloc = [&](size_t bytes) {
        void* p = w + off;
        off += (bytes + 255) & ~(size_t)255;
        return p;
    };
    float*  x      = (float*) alloc((size_t)N * DMODEL * 4);
    float*  rn     = (float*) alloc((size_t)E * 3 * 4);
    float*  bl     = (float*) alloc(((size_t)E + 64) * 4);
    int*    cnt    = (int*)   alloc((size_t)E * 4);
    int*    rowp   = (int*)   alloc(((size_t)E + 1) * 4);
    int*    bsum   = (int*)   alloc(4096);
    int2*   packed = (int2*)  alloc((size_t)T * 8);
    int*    eids   = (int*)   alloc((size_t)T * 4);
    float*  logits = (float*) alloc((size_t)T * 4);
    int*    ecnt   = (int*)   alloc((size_t)N * 4);
    int*    erowp  = (int*)   alloc(((size_t)N + 1) * 4);
    int*    eord   = (int*)   alloc((size_t)E * 4);
    float*  xs     = (float*) alloc((size_t)N * DM * 4);
    float*  xd     = (float*) alloc((size_t)N * DM * 4);
    bf16_t* xij    = (bf16_t*)alloc((size_t)E * DM * 2);
    bf16_t* msg    = (bf16_t*)alloc((size_t)E * DM * 2);
    bf16_t* ft     = (bf16_t*)alloc((size_t)(N + 64) * DM * 2);
    bf16_t* hb     = (bf16_t*)alloc((size_t)(N + 64) * HDIM * 2);
    bf16_t* W1t    = (bf16_t*)alloc((size_t)3 * HDIM * DM * 2);
    bf16_t* W2t    = (bf16_t*)alloc((size_t)3 * DMODEL * HDIM * 2);
    bf16_t* Wedgt  = (bf16_t*)alloc((size_t)3 * DM * DMODEL * 2);
    float*  accs   = (float*) alloc(64);
    (void)ws_size; (void)n_in; (void)out_size;

    const int nbScanE = (E + 255) / 256;
    const int nbScanN = (N + 255) / 256;

    // ---- setup (layer-invariant) ----
    k_embed<<<N, 256, 0, stream>>>(an, emb, x);
    k_edge_geom<<<(E + 255) / 256, 256, 0, stream>>>(r, bl, rn, E);
    // weight transposes/casts for MFMA kernels (all layers)
    for (int l = 0; l < 3; ++l) {
        k_castT<<<dim3(DM / 32, HDIM / 32), 256, 0, stream>>>(
            W1 + (size_t)l * DM * HDIM, W1t + (size_t)l * HDIM * DM, DM, HDIM);
        k_castT<<<dim3(HDIM / 32, DMODEL / 32), 256, 0, stream>>>(
            W2 + (size_t)l * HDIM * DMODEL, W2t + (size_t)l * DMODEL * HDIM,
            HDIM, DMODEL);
        k_castT<<<dim3(DMODEL / 32, DM / 32), 256, 0, stream>>>(
            Wedge + (size_t)l * DMODEL * DM, Wedgt + (size_t)l * DM * DMODEL,
            DMODEL, DM);
    }
    // triplet CSR by t_dst
    hipMemsetAsync(cnt, 0, (size_t)E * 4, stream);
    k_hist<<<(T + 255) / 256, 256, 0, stream>>>(td, cnt, T);
    k_scan_part<<<nbScanE, 256, 0, stream>>>(cnt, bsum, E);
    k_scan_mid<<<1, 1024, 0, stream>>>(bsum, nbScanE);
    k_scan_final<<<nbScanE, 256, 0, stream>>>(cnt, bsum, rowp, E, T);
    hipMemsetAsync(cnt, 0, (size_t)E * 4, stream);
    k_scatter<<<(T + 255) / 256, 256, 0, stream>>>(ts, td, rowp, cnt, rn,
                                                   packed, T);
    k_fill_eids<<<(E + 255) / 256, 256, 0, stream>>>(rowp, eids, E);
    // edge CSR by gd
    hipMemsetAsync(ecnt, 0, (size_t)N * 4, stream);
    k_hist<<<(E + 255) / 256, 256, 0, stream>>>(gd, ecnt, E);
    k_scan_part<<<nbScanN, 256, 0, stream>>>(ecnt, bsum, N);
    k_scan_mid<<<1, 1024, 0, stream>>>(bsum, nbScanN);
    k_scan_final<<<nbScanN, 256, 0, stream>>>(ecnt, bsum, erowp, N, E);
    hipMemsetAsync(ecnt, 0, (size_t)N * 4, stream);
    k_escatter<<<(E + 255) / 256, 256, 0, stream>>>(gd, erowp, ecnt, eord, E);

    // ---- layers ----
    for (int l = 0; l < 3; ++l) {
        k_node_proj<<<(N + 3) / 4, 256, 0, stream>>>(
            x, Wsrc + l * DMODEL * DM, bsrc + l * DM,
            Wdst + l * DMODEL * DM, bdst + l * DM, xs, xd, N);
        k_xij<<<(E + 63) / 64, 256, 0, stream>>>(
            bl, Wedgt + (size_t)l * DM * DMODEL, bedge + l * DM,
            xs, xd, gs, gd, xij, E);
        k_logit<<<(T + 255) / 256, 256, 0, stream>>>(
            xij, packed, eids, attn + l * DM, logits, T);
        k_attend<<<(E * 16 + 255) / 256, 256, 0, stream>>>(
            xij, logits, packed, rowp, msg, E);
        k_aggregate<<<(N * 16 + 255) / 256, 256, 0, stream>>>(
            msg, erowp, eord, ft, N);
        k_ffn1<<<dim3((N + 63) / 64, HDIM / 64), 256, 0, stream>>>(
            ft, W1t + (size_t)l * HDIM * DM, b1 + l * HDIM, hb, N);
        k_ffn2<<<dim3((N + 63) / 64, DMODEL / 64), 256, 0, stream>>>(
            hb, W2t + (size_t)l * DMODEL * HDIM, b2 + l * DMODEL, x, N);
    }

    // ---- output head ----
    hipMemsetAsync(accs, 0, 4, stream);
    k_out_reduce<<<120, 256, 0, stream>>>(x, Wfc, accs, N * DMODEL);
    k_out_final<<<1, 1, 0, stream>>>(accs, bfc, (float*)d_out, 1.0f / (float)N);
}

// Round 12
// 1120.735 us; speedup vs baseline: 1.4215x; 1.1249x over previous
//
#include <hip/hip_runtime.h>
#include <math.h>

// M3GNet-like GNN forward. N=10000 nodes, E=160000 edges, T=1200000 triplets,
// D=256, DM=64, H=1024, L=3, output = scalar mean energy (fp32).
//
// R11: k_node_proj -> MFMA (was latency-bound: 256 serial K-iters, VALUBusy
// 9.8%). Node features x now bf16 end-to-end (k_embed packs, k_ffn2 packs,
// k_out_reduce unpacks). Wsrc/Wdst cast+transposed in setup. One kernel
// computes xs and xd (64 MFMA/wave), no LDS, no barriers.

#define DM 64
#define DMODEL 256
#define HDIM 1024

typedef unsigned short bf16_t;
typedef __attribute__((ext_vector_type(8))) short s8v;    // 8 bf16 (4 VGPRs)
typedef __attribute__((ext_vector_type(4))) float f4;     // MFMA acc

__device__ __forceinline__ bf16_t f2bf(float f) {
    unsigned int u = __float_as_uint(f);
    return (bf16_t)((u + 0x7FFFu + ((u >> 16) & 1u)) >> 16);   // RNE
}
__device__ __forceinline__ float bf_lo(unsigned int u) {
    return __uint_as_float(u << 16);
}
__device__ __forceinline__ float bf_hi(unsigned int u) {
    return __uint_as_float(u & 0xFFFF0000u);
}

__global__ void k_embed(const int* __restrict__ an, const float* __restrict__ emb,
                        bf16_t* __restrict__ x) {
    int n = blockIdx.x;
    int d = threadIdx.x;
    x[n * DMODEL + d] = f2bf(emb[an[n] * DMODEL + d]);
}

__global__ void k_edge_geom(const float* __restrict__ r, float* __restrict__ bl,
                            float* __restrict__ rn, int E) {
    int e = blockIdx.x * blockDim.x + threadIdx.x;
    if (e >= E) return;
    float a = r[e * 3 + 0], b = r[e * 3 + 1], c = r[e * 3 + 2];
    float l = sqrtf(a * a + b * b + c * c);
    bl[e] = l;
    float inv = 1.0f / l;
    rn[e * 3 + 0] = a * inv;
    rn[e * 3 + 1] = b * inv;
    rn[e * 3 + 2] = c * inv;
}

__global__ void k_hist(const int* __restrict__ idx, int* __restrict__ cnt, int M) {
    int t = blockIdx.x * blockDim.x + threadIdx.x;
    if (t < M) atomicAdd(&cnt[idx[t]], 1);
}

// ---- 3-phase exclusive scan ----
__global__ __launch_bounds__(256) void k_scan_part(
    const int* __restrict__ cnt, int* __restrict__ bsum, int M) {
    __shared__ int sm[4];
    int tid = threadIdx.x;
    int i = blockIdx.x * 256 + tid;
    int v = (i < M) ? cnt[i] : 0;
    for (int off = 32; off > 0; off >>= 1) v += __shfl_xor(v, off, 64);
    if ((tid & 63) == 0) sm[tid >> 6] = v;
    __syncthreads();
    if (tid == 0) bsum[blockIdx.x] = sm[0] + sm[1] + sm[2] + sm[3];
}

__global__ __launch_bounds__(1024) void k_scan_mid(int* __restrict__ bsum, int nb) {
    __shared__ int sm[1024];
    int tid = threadIdx.x;
    int v = (tid < nb) ? bsum[tid] : 0;
    sm[tid] = v;
    __syncthreads();
    for (int off = 1; off < 1024; off <<= 1) {
        int u = (tid >= off) ? sm[tid - off] : 0;
        __syncthreads();
        sm[tid] += u;
        __syncthreads();
    }
    if (tid < nb) bsum[tid] = sm[tid] - v;
}

__global__ __launch_bounds__(256) void k_scan_final(
    const int* __restrict__ cnt, const int* __restrict__ bsum,
    int* __restrict__ rowp, int M, int total) {
    __shared__ int sm[256];
    int tid = threadIdx.x;
    int i = blockIdx.x * 256 + tid;
    int v = (i < M) ? cnt[i] : 0;
    sm[tid] = v;
    __syncthreads();
    for (int off = 1; off < 256; off <<= 1) {
        int u = (tid >= off) ? sm[tid - off] : 0;
        __syncthreads();
        sm[tid] += u;
        __syncthreads();
    }
    if (i < M) rowp[i] = bsum[blockIdx.x] + sm[tid] - v;
    if (i == 0) rowp[M] = total;
}

__global__ void k_scatter(const int* __restrict__ ts, const int* __restrict__ td,
                          const int* __restrict__ rowp, int* __restrict__ cursor,
                          const float* __restrict__ rn,
                          int2* __restrict__ packed, int T) {
    int t = blockIdx.x * blockDim.x + threadIdx.x;
    if (t >= T) return;
    int a = ts[t], b = td[t];
    float d = rn[a * 3 + 0] * rn[b * 3 + 0]
            + rn[a * 3 + 1] * rn[b * 3 + 1]
            + rn[a * 3 + 2] * rn[b * 3 + 2];
    d = fminf(1.0f, fmaxf(-1.0f, d));
    int pos = rowp[b] + atomicAdd(&cursor[b], 1);
    packed[pos] = make_int2(a, __float_as_int(d));
}

__global__ void k_fill_eids(const int* __restrict__ rowp, int* __restrict__ eids,
                            int E) {
    int e = blockIdx.x * blockDim.x + threadIdx.x;
    if (e >= E) return;
    int beg = rowp[e], end = rowp[e + 1];
    for (int p = beg; p < end; ++p) eids[p] = e;
}

__global__ void k_escatter(const int* __restrict__ gd, const int* __restrict__ erowp,
                           int* __restrict__ cursor, int* __restrict__ eord, int E) {
    int e = blockIdx.x * blockDim.x + threadIdx.x;
    if (e >= E) return;
    int n = gd[e];
    int pos = erowp[n] + atomicAdd(&cursor[n], 1);
    eord[pos] = e;
}

// 32x32 tiled transpose + cast: src fp32 [K][Nn] -> dst bf16 [Nn][K].
__global__ __launch_bounds__(256) void k_castT(
    const float* __restrict__ src, bf16_t* __restrict__ dst, int K, int Nn) {
    __shared__ float tile[32][33];
    int k0 = blockIdx.x * 32, n0 = blockIdx.y * 32;
    int tx = threadIdx.x & 31, ty = threadIdx.x >> 5;
    #pragma unroll
    for (int i = 0; i < 4; ++i) {
        int row = ty + i * 8;
        tile[row][tx] = src[(size_t)(k0 + row) * Nn + n0 + tx];
    }
    __syncthreads();
    #pragma unroll
    for (int i = 0; i < 4; ++i) {
        int row = ty + i * 8;
        dst[(size_t)(n0 + row) * K + k0 + tx] = f2bf(tile[tx][row]);
    }
}

// MFMA node_proj: xs = x@Wsrc + bs, xd = x@Wdst + bd (fp32 out).
// wave = 16 nodes x 64 cols, both projections. grid ceil(N/64).
__global__ __launch_bounds__(256) void k_node_proj(
    const bf16_t* __restrict__ xb,
    const bf16_t* __restrict__ Wst, const float* __restrict__ bs,
    const bf16_t* __restrict__ Wdt, const float* __restrict__ bd,
    float* __restrict__ xs, float* __restrict__ xd, int N) {
    int tid = threadIdx.x;
    int w = tid >> 6, lane = tid & 63;
    int col = lane & 15, quad = lane >> 4;
    int m0 = blockIdx.x * 64 + w * 16;
    f4 as[4] = {{0.f,0.f,0.f,0.f},{0.f,0.f,0.f,0.f},
                {0.f,0.f,0.f,0.f},{0.f,0.f,0.f,0.f}};
    f4 ad[4] = {{0.f,0.f,0.f,0.f},{0.f,0.f,0.f,0.f},
                {0.f,0.f,0.f,0.f},{0.f,0.f,0.f,0.f}};
    #pragma unroll
    for (int k0 = 0; k0 < DMODEL; k0 += 32) {
        s8v a = *(const s8v*)&xb[(size_t)(m0 + col) * DMODEL + k0 + quad * 8];
        #pragma unroll
        for (int t = 0; t < 4; ++t) {
            s8v b1v = *(const s8v*)&Wst[(size_t)(t * 16 + col) * DMODEL + k0 + quad * 8];
            as[t] = __builtin_amdgcn_mfma_f32_16x16x32_bf16(a, b1v, as[t], 0, 0, 0);
            s8v b2v = *(const s8v*)&Wdt[(size_t)(t * 16 + col) * DMODEL + k0 + quad * 8];
            ad[t] = __builtin_amdgcn_mfma_f32_16x16x32_bf16(a, b2v, ad[t], 0, 0, 0);
        }
    }
    #pragma unroll
    for (int t = 0; t < 4; ++t) {
        int c = t * 16 + col;
        float bsv = bs[c], bdv = bd[c];
        #pragma unroll
        for (int r = 0; r < 4; ++r) {
            int m = m0 + quad * 4 + r;
            if (m < N) {
                xs[(size_t)m * DM + c] = as[t][r] + bsv;
                xd[(size_t)m * DM + c] = ad[t][r] + bdv;
            }
        }
    }
}

// MFMA k_xij: xij[e][c] = (RBF(bl[e]) @ Wedge)[c] + xs[gs[e]][c] + xd[gd[e]][c] + be[c]
__global__ __launch_bounds__(256) void k_xij(
    const float* __restrict__ bl, const bf16_t* __restrict__ Wedgt,
    const float* __restrict__ be,
    const float* __restrict__ xs, const float* __restrict__ xd,
    const int* __restrict__ gs, const int* __restrict__ gd,
    bf16_t* __restrict__ xij, int E) {
    int tid = threadIdx.x;
    int w = tid >> 6, lane = tid & 63;
    int col = lane & 15, quad = lane >> 4;
    int m0 = blockIdx.x * 64 + w * 16;
    const float step = 8.0f / 255.0f;
    const float gamma = (255.0f / 8.0f) * (255.0f / 8.0f);
    int me = m0 + col;
    float blv = (me < E) ? bl[me] : 0.f;
    f4 acc[4] = {{0.f,0.f,0.f,0.f},{0.f,0.f,0.f,0.f},
                 {0.f,0.f,0.f,0.f},{0.f,0.f,0.f,0.f}};
    #pragma unroll
    for (int k0 = 0; k0 < DMODEL; k0 += 32) {
        s8v a;
        #pragma unroll
        for (int j = 0; j < 8; ++j) {
            float c = (float)(k0 + quad * 8 + j) * step;
            float dd = blv - c;
            a[j] = (short)f2bf(__expf(-gamma * dd * dd));
        }
        #pragma unroll
        for (int t = 0; t < 4; ++t) {
            s8v b = *(const s8v*)&Wedgt[(size_t)(t * 16 + col) * DMODEL + k0 + quad * 8];
            acc[t] = __builtin_amdgcn_mfma_f32_16x16x32_bf16(a, b, acc[t], 0, 0, 0);
        }
    }
    #pragma unroll
    for (int r = 0; r < 4; ++r) {
        int e = m0 + quad * 4 + r;
        if (e >= E) continue;
        int s = gs[e], d2 = gd[e];
        #pragma unroll
        for (int t = 0; t < 4; ++t) {
            int c = t * 16 + col;
            float v = acc[t][r] + xs[(size_t)s * DM + c] + xd[(size_t)d2 * DM + c] + be[c];
            xij[(size_t)e * DM + c] = f2bf(v);
        }
    }
}

// thread per triplet: Chebyshev + silu dot; bf16 row gathers.
__global__ __launch_bounds__(256) void k_logit(
    const bf16_t* __restrict__ xij, const int2* __restrict__ packed,
    const int* __restrict__ eids,
    const float* __restrict__ attn_l, float* __restrict__ logits, int T) {
    int p = blockIdx.x * 256 + threadIdx.x;
    if (p >= T) return;
    int2 pk = packed[p];
    int s = pk.x;
    float c = __int_as_float(pk.y);
    int e = eids[p];
    float c2 = 2.0f * c;
    const uint4* xsr = (const uint4*)(xij + (size_t)s * DM);
    const uint4* xer = (const uint4*)(xij + (size_t)e * DM);
    float t0 = 1.0f, t1 = c;
    float acc = 0.f;
    #pragma unroll
    for (int j = 0; j < 8; ++j) {
        uint4 a4 = xsr[j];
        uint4 b4 = xer[j];
        unsigned int au[4] = {a4.x, a4.y, a4.z, a4.w};
        unsigned int bu[4] = {b4.x, b4.y, b4.z, b4.w};
        #pragma unroll
        for (int q = 0; q < 4; ++q) {
            float us[2] = {bf_lo(au[q]) + bf_lo(bu[q]),
                           bf_hi(au[q]) + bf_hi(bu[q])};
            #pragma unroll
            for (int m = 0; m < 2; ++m) {
                int k = j * 8 + q * 2 + m;
                float tk;
                if (k == 0)      tk = 1.0f;
                else if (k == 1) tk = c;
                else { tk = fmaf(c2, t1, -t0); t0 = t1; t1 = tk; }
                float v = tk + us[m];
                float sl = v / (1.0f + __expf(-v));
                acc = fmaf(sl, attn_l[k], acc);
            }
        }
    }
    logits[p] = acc;
}

// thread per (edge, channel-quad): softmax + weighted bf16 gather; bf16 store.
__global__ __launch_bounds__(256) void k_attend(
    const bf16_t* __restrict__ xij, const float* __restrict__ logits,
    const int2* __restrict__ packed, const int* __restrict__ rowp,
    bf16_t* __restrict__ msg, int E) {
    int gtid = blockIdx.x * 256 + threadIdx.x;
    int e = gtid >> 4;
    if (e >= E) return;
    int quad = gtid & 15;
    int beg = rowp[e], end = rowp[e + 1];
    float a0 = 0.f, a1 = 0.f, a2 = 0.f, a3 = 0.f;
    if (beg < end) {
        float lm = -1e30f;
        for (int p = beg; p < end; ++p) lm = fmaxf(lm, logits[p]);
        float den = 0.f;
        for (int p = beg; p < end; ++p) {
            float w = __expf(logits[p] - lm);
            den += w;
            int s = packed[p].x;
            uint2 uv = *(const uint2*)&xij[(size_t)s * DM + quad * 4];
            a0 = fmaf(w, bf_lo(uv.x), a0);
            a1 = fmaf(w, bf_hi(uv.x), a1);
            a2 = fmaf(w, bf_lo(uv.y), a2);
            a3 = fmaf(w, bf_hi(uv.y), a3);
        }
        float inv = 1.0f / den;
        a0 *= inv; a1 *= inv; a2 *= inv; a3 *= inv;
    }
    ushort4 o = {f2bf(a0), f2bf(a1), f2bf(a2), f2bf(a3)};
    *(ushort4*)&msg[(size_t)e * DM + quad * 4] = o;
}

// thread per (node, channel-quad): sum bf16 msg -> bf16 ft.
__global__ __launch_bounds__(256) void k_aggregate(
    const bf16_t* __restrict__ msg, const int* __restrict__ erowp,
    const int* __restrict__ eord, bf16_t* __restrict__ ft, int N) {
    int gtid = blockIdx.x * 256 + threadIdx.x;
    int n = gtid >> 4;
    if (n >= N) return;
    int quad = gtid & 15;
    int beg = erowp[n], end = erowp[n + 1];
    float a0 = 0.f, a1 = 0.f, a2 = 0.f, a3 = 0.f;
    for (int j = beg; j < end; ++j) {
        uint2 uv = *(const uint2*)&msg[(size_t)eord[j] * DM + quad * 4];
        a0 += bf_lo(uv.x); a1 += bf_hi(uv.x);
        a2 += bf_lo(uv.y); a3 += bf_hi(uv.y);
    }
    ushort4 o = {f2bf(a0), f2bf(a1), f2bf(a2), f2bf(a3)};
    *(ushort4*)&ft[(size_t)n * DM + quad * 4] = o;
}

// MFMA ffn1: h = silu(ft(bf16) @ W1 + b1), h bf16. grid (157, 16).
__global__ __launch_bounds__(256) void k_ffn1(
    const bf16_t* __restrict__ ft, const bf16_t* __restrict__ W1t,
    const float* __restrict__ b1, bf16_t* __restrict__ h, int N) {
    int tid = threadIdx.x;
    int w = tid >> 6, lane = tid & 63;
    int col = lane & 15, quad = lane >> 4;
    int m0 = blockIdx.x * 64 + w * 16;
    int c0 = blockIdx.y * 64;
    f4 acc[4] = {{0.f,0.f,0.f,0.f},{0.f,0.f,0.f,0.f},
                 {0.f,0.f,0.f,0.f},{0.f,0.f,0.f,0.f}};
    #pragma unroll
    for (int k0 = 0; k0 < DM; k0 += 32) {
        s8v a = *(const s8v*)&ft[(size_t)(m0 + col) * DM + k0 + quad * 8];
        #pragma unroll
        for (int t = 0; t < 4; ++t) {
            s8v b = *(const s8v*)&W1t[(size_t)(c0 + t * 16 + col) * DM + k0 + quad * 8];
            acc[t] = __builtin_amdgcn_mfma_f32_16x16x32_bf16(a, b, acc[t], 0, 0, 0);
        }
    }
    #pragma unroll
    for (int t = 0; t < 4; ++t) {
        int c = c0 + t * 16 + col;
        float bb = b1[c];
        #pragma unroll
        for (int r = 0; r < 4; ++r) {
            int m = m0 + quad * 4 + r;
            if (m < N) {
                float v = acc[t][r] + bb;
                h[(size_t)m * HDIM + c] = f2bf(v / (1.0f + __expf(-v)));
            }
        }
    }
}

// MFMA ffn2: x = h(bf16) @ W2 + b2 (bf16 out). grid (157, 4).
__global__ __launch_bounds__(256) void k_ffn2(
    const bf16_t* __restrict__ h, const bf16_t* __restrict__ W2t,
    const float* __restrict__ b2, bf16_t* __restrict__ x, int N) {
    int tid = threadIdx.x;
    int w = tid >> 6, lane = tid & 63;
    int col = lane & 15, quad = lane >> 4;
    int m0 = blockIdx.x * 64 + w * 16;
    int c0 = blockIdx.y * 64;
    f4 acc[4] = {{0.f,0.f,0.f,0.f},{0.f,0.f,0.f,0.f},
                 {0.f,0.f,0.f,0.f},{0.f,0.f,0.f,0.f}};
    for (int k0 = 0; k0 < HDIM; k0 += 32) {
        s8v a = *(const s8v*)&h[(size_t)(m0 + col) * HDIM + k0 + quad * 8];
        #pragma unroll
        for (int t = 0; t < 4; ++t) {
            s8v b = *(const s8v*)&W2t[(size_t)(c0 + t * 16 + col) * HDIM + k0 + quad * 8];
            acc[t] = __builtin_amdgcn_mfma_f32_16x16x32_bf16(a, b, acc[t], 0, 0, 0);
        }
    }
    #pragma unroll
    for (int t = 0; t < 4; ++t) {
        int c = c0 + t * 16 + col;
        float bb = b2[c];
        #pragma unroll
        for (int r = 0; r < 4; ++r) {
            int m = m0 + quad * 4 + r;
            if (m < N) x[(size_t)m * DMODEL + c] = f2bf(acc[t][r] + bb);
        }
    }
}

// grid-stride dot over bf16 x, one atomic per block.
__global__ __launch_bounds__(256) void k_out_reduce(
    const bf16_t* __restrict__ x, const float* __restrict__ Wfc,
    float* __restrict__ acc, int NT) {
    __shared__ float sm[4];
    int tid = threadIdx.x;
    float v = 0.f;
    int np = NT / 2;
    const unsigned int* xp = (const unsigned int*)x;
    for (int i = blockIdx.x * blockDim.x + tid; i < np; i += gridDim.x * blockDim.x) {
        unsigned int u = xp[i];
        int c = (2 * i) & (DMODEL - 1);
        v = fmaf(bf_lo(u), Wfc[c], v);
        v = fmaf(bf_hi(u), Wfc[c + 1], v);
    }
    for (int off = 32; off > 0; off >>= 1) v += __shfl_xor(v, off, 64);
    if ((tid & 63) == 0) sm[tid >> 6] = v;
    __syncthreads();
    if (tid == 0) {
        float s = sm[0] + sm[1] + sm[2] + sm[3];
        atomicAdd(acc, s);
    }
}

__global__ void k_out_final(const float* __restrict__ acc, const float* __restrict__ bfc,
                            float* __restrict__ out, float invN) {
    out[0] = acc[0] * invN + bfc[0];
}

extern "C" void kernel_launch(void* const* d_in, const int* in_sizes, int n_in,
                              void* d_out, int out_size, void* d_ws, size_t ws_size,
                              hipStream_t stream) {
    const int*   an    = (const int*)d_in[0];
    const int*   gs    = (const int*)d_in[1];
    const int*   gd    = (const int*)d_in[2];
    const int*   ts    = (const int*)d_in[3];
    const int*   td    = (const int*)d_in[4];
    const float* r     = (const float*)d_in[5];
    const float* emb   = (const float*)d_in[6];
    const float* Wsrc  = (const float*)d_in[7];
    const float* bsrc  = (const float*)d_in[8];
    const float* Wdst  = (const float*)d_in[9];
    const float* bdst  = (const float*)d_in[10];
    const float* Wedge = (const float*)d_in[11];
    const float* bedge = (const float*)d_in[12];
    const float* attn  = (const float*)d_in[13];
    const float* W1    = (const float*)d_in[14];
    const float* b1    = (const float*)d_in[15];
    const float* W2    = (const float*)d_in[16];
    const float* b2    = (const float*)d_in[17];
    const float* Wfc   = (const float*)d_in[18];
    const float* bfc   = (const float*)d_in[19];

    const int N = in_sizes[0];
    const int E = in_sizes[1];
    const int T = in_sizes[3];

    char* w = (char*)d_ws;
    size_t off = 0;
    auto alloc = [&](size_t bytes) {
        void* p = w + off;
        off += (bytes + 255) & ~(size_t)255;
        return p;
    };
    bf16_t* xb     = (bf16_t*)alloc((size_t)(N + 64) * DMODEL * 2);
    float*  rn     = (float*) alloc((size_t)E * 3 * 4);
    float*  bl     = (float*) alloc(((size_t)E + 64) * 4);
    int*    cnt    = (int*)   alloc((size_t)E * 4);
    int*    rowp   = (int*)   alloc(((size_t)E + 1) * 4);
    int*    bsum   = (int*)   alloc(4096);
    int2*   packed = (int2*)  alloc((size_t)T * 8);
    int*    eids   = (int*)   alloc((size_t)T * 4);
    float*  logits = (float*) alloc((size_t)T * 4);
    int*    ecnt   = (int*)   alloc((size_t)N * 4);
    int*    erowp  = (int*)   alloc(((size_t)N + 1) * 4);
    int*    eord   = (int*)   alloc((size_t)E * 4);
    float*  xs     = (float*) alloc((size_t)N * DM * 4);
    float*  xd     = (float*) alloc((size_t)N * DM * 4);
    bf16_t* xij    = (bf16_t*)alloc((size_t)E * DM * 2);
    bf16_t* msg    = (bf16_t*)alloc((size_t)E * DM * 2);
    bf16_t* ft     = (bf16_t*)alloc((size_t)(N + 64) * DM * 2);
    bf16_t* hb     = (bf16_t*)alloc((size_t)(N + 64) * HDIM * 2);
    bf16_t* W1t    = (bf16_t*)alloc((size_t)3 * HDIM * DM * 2);
    bf16_t* W2t    = (bf16_t*)alloc((size_t)3 * DMODEL * HDIM * 2);
    bf16_t* Wedgt  = (bf16_t*)alloc((size_t)3 * DM * DMODEL * 2);
    bf16_t* Wst    = (bf16_t*)alloc((size_t)3 * DM * DMODEL * 2);
    bf16_t* Wdt    = (bf16_t*)alloc((size_t)3 * DM * DMODEL * 2);
    float*  accs   = (float*) alloc(64);
    (void)ws_size; (void)n_in; (void)out_size;

    const int nbScanE = (E + 255) / 256;
    const int nbScanN = (N + 255) / 256;

    // ---- setup (layer-invariant) ----
    k_embed<<<N, 256, 0, stream>>>(an, emb, xb);
    k_edge_geom<<<(E + 255) / 256, 256, 0, stream>>>(r, bl, rn, E);
    // weight transposes/casts for MFMA kernels (all layers)
    for (int l = 0; l < 3; ++l) {
        k_castT<<<dim3(DM / 32, HDIM / 32), 256, 0, stream>>>(
            W1 + (size_t)l * DM * HDIM, W1t + (size_t)l * HDIM * DM, DM, HDIM);
        k_castT<<<dim3(HDIM / 32, DMODEL / 32), 256, 0, stream>>>(
            W2 + (size_t)l * HDIM * DMODEL, W2t + (size_t)l * DMODEL * HDIM,
            HDIM, DMODEL);
        k_castT<<<dim3(DMODEL / 32, DM / 32), 256, 0, stream>>>(
            Wedge + (size_t)l * DMODEL * DM, Wedgt + (size_t)l * DM * DMODEL,
            DMODEL, DM);
        k_castT<<<dim3(DMODEL / 32, DM / 32), 256, 0, stream>>>(
            Wsrc + (size_t)l * DMODEL * DM, Wst + (size_t)l * DM * DMODEL,
            DMODEL, DM);
        k_castT<<<dim3(DMODEL / 32, DM / 32), 256, 0, stream>>>(
            Wdst + (size_t)l * DMODEL * DM, Wdt + (size_t)l * DM * DMODEL,
            DMODEL, DM);
    }
    // triplet CSR by t_dst
    hipMemsetAsync(cnt, 0, (size_t)E * 4, stream);
    k_hist<<<(T + 255) / 256, 256, 0, stream>>>(td, cnt, T);
    k_scan_part<<<nbScanE, 256, 0, stream>>>(cnt, bsum, E);
    k_scan_mid<<<1, 1024, 0, stream>>>(bsum, nbScanE);
    k_scan_final<<<nbScanE, 256, 0, stream>>>(cnt, bsum, rowp, E, T);
    hipMemsetAsync(cnt, 0, (size_t)E * 4, stream);
    k_scatter<<<(T + 255) / 256, 256, 0, stream>>>(ts, td, rowp, cnt, rn,
                                                   packed, T);
    k_fill_eids<<<(E + 255) / 256, 256, 0, stream>>>(rowp, eids, E);
    // edge CSR by gd
    hipMemsetAsync(ecnt, 0, (size_t)N * 4, stream);
    k_hist<<<(E + 255) / 256, 256, 0, stream>>>(gd, ecnt, E);
    k_scan_part<<<nbScanN, 256, 0, stream>>>(ecnt, bsum, N);
    k_scan_mid<<<1, 1024, 0, stream>>>(bsum, nbScanN);
    k_scan_final<<<nbScanN, 256, 0, stream>>>(ecnt, bsum, erowp, N, E);
    hipMemsetAsync(ecnt, 0, (size_t)N * 4, stream);
    k_escatter<<<(E + 255) / 256, 256, 0, stream>>>(gd, erowp, ecnt, eord, E);

    // ---- layers ----
    for (int l = 0; l < 3; ++l) {
        k_node_proj<<<(N + 63) / 64, 256, 0, stream>>>(
            xb, Wst + (size_t)l * DM * DMODEL, bsrc + l * DM,
            Wdt + (size_t)l * DM * DMODEL, bdst + l * DM, xs, xd, N);
        k_xij<<<(E + 63) / 64, 256, 0, stream>>>(
            bl, Wedgt + (size_t)l * DM * DMODEL, bedge + l * DM,
            xs, xd, gs, gd, xij, E);
        k_logit<<<(T + 255) / 256, 256, 0, stream>>>(
            xij, packed, eids, attn + l * DM, logits, T);
        k_attend<<<(E * 16 + 255) / 256, 256, 0, stream>>>(
            xij, logits, packed, rowp, msg, E);
        k_aggregate<<<(N * 16 + 255) / 256, 256, 0, stream>>>(
            msg, erowp, eord, ft, N);
        k_ffn1<<<dim3((N + 63) / 64, HDIM / 64), 256, 0, stream>>>(
            ft, W1t + (size_t)l * HDIM * DM, b1 + l * HDIM, hb, N);
        k_ffn2<<<dim3((N + 63) / 64, DMODEL / 64), 256, 0, stream>>>(
            hb, W2t + (size_t)l * DMODEL * HDIM, b2 + l * DMODEL, xb, N);
    }

    // ---- output head ----
    hipMemsetAsync(accs, 0, 4, stream);
    k_out_reduce<<<120, 256, 0, stream>>>(xb, Wfc, accs, N * DMODEL);
    k_out_final<<<1, 1, 0, stream>>>(accs, bfc, (float*)d_out, 1.0f / (float)N);
}

// Round 13
// 1087.436 us; speedup vs baseline: 1.4651x; 1.0306x over previous
//
#include <hip/hip_runtime.h>
#include <math.h>

// M3GNet-like GNN forward. N=10000 nodes, E=160000 edges, T=1200000 triplets,
// D=256, DM=64, H=1024, L=3, output = scalar mean energy (fp32).
//
// R12: fuse k_logit + k_attend -> k_edge_attn (16-lane group per edge,
// lane = channel-quad). Each src row is gathered ONCE (was twice: 300 MB
// -> 150 MB/layer); logits/eids buffers and k_fill_eids deleted. Chebyshev
// T_k via complex rotation (z^{4q} binary ladder, no acos); 4-step
// __shfl_xor logit reduce (stays inside the 16-lane group); online softmax.

#define DM 64
#define DMODEL 256
#define HDIM 1024

typedef unsigned short bf16_t;
typedef __attribute__((ext_vector_type(8))) short s8v;    // 8 bf16 (4 VGPRs)
typedef __attribute__((ext_vector_type(4))) float f4;     // MFMA acc

__device__ __forceinline__ bf16_t f2bf(float f) {
    unsigned int u = __float_as_uint(f);
    return (bf16_t)((u + 0x7FFFu + ((u >> 16) & 1u)) >> 16);   // RNE
}
__device__ __forceinline__ float bf_lo(unsigned int u) {
    return __uint_as_float(u << 16);
}
__device__ __forceinline__ float bf_hi(unsigned int u) {
    return __uint_as_float(u & 0xFFFF0000u);
}

__global__ void k_embed(const int* __restrict__ an, const float* __restrict__ emb,
                        bf16_t* __restrict__ x) {
    int n = blockIdx.x;
    int d = threadIdx.x;
    x[n * DMODEL + d] = f2bf(emb[an[n] * DMODEL + d]);
}

__global__ void k_edge_geom(const float* __restrict__ r, float* __restrict__ bl,
                            float* __restrict__ rn, int E) {
    int e = blockIdx.x * blockDim.x + threadIdx.x;
    if (e >= E) return;
    float a = r[e * 3 + 0], b = r[e * 3 + 1], c = r[e * 3 + 2];
    float l = sqrtf(a * a + b * b + c * c);
    bl[e] = l;
    float inv = 1.0f / l;
    rn[e * 3 + 0] = a * inv;
    rn[e * 3 + 1] = b * inv;
    rn[e * 3 + 2] = c * inv;
}

__global__ void k_hist(const int* __restrict__ idx, int* __restrict__ cnt, int M) {
    int t = blockIdx.x * blockDim.x + threadIdx.x;
    if (t < M) atomicAdd(&cnt[idx[t]], 1);
}

// ---- 3-phase exclusive scan ----
__global__ __launch_bounds__(256) void k_scan_part(
    const int* __restrict__ cnt, int* __restrict__ bsum, int M) {
    __shared__ int sm[4];
    int tid = threadIdx.x;
    int i = blockIdx.x * 256 + tid;
    int v = (i < M) ? cnt[i] : 0;
    for (int off = 32; off > 0; off >>= 1) v += __shfl_xor(v, off, 64);
    if ((tid & 63) == 0) sm[tid >> 6] = v;
    __syncthreads();
    if (tid == 0) bsum[blockIdx.x] = sm[0] + sm[1] + sm[2] + sm[3];
}

__global__ __launch_bounds__(1024) void k_scan_mid(int* __restrict__ bsum, int nb) {
    __shared__ int sm[1024];
    int tid = threadIdx.x;
    int v = (tid < nb) ? bsum[tid] : 0;
    sm[tid] = v;
    __syncthreads();
    for (int off = 1; off < 1024; off <<= 1) {
        int u = (tid >= off) ? sm[tid - off] : 0;
        __syncthreads();
        sm[tid] += u;
        __syncthreads();
    }
    if (tid < nb) bsum[tid] = sm[tid] - v;
}

__global__ __launch_bounds__(256) void k_scan_final(
    const int* __restrict__ cnt, const int* __restrict__ bsum,
    int* __restrict__ rowp, int M, int total) {
    __shared__ int sm[256];
    int tid = threadIdx.x;
    int i = blockIdx.x * 256 + tid;
    int v = (i < M) ? cnt[i] : 0;
    sm[tid] = v;
    __syncthreads();
    for (int off = 1; off < 256; off <<= 1) {
        int u = (tid >= off) ? sm[tid - off] : 0;
        __syncthreads();
        sm[tid] += u;
        __syncthreads();
    }
    if (i < M) rowp[i] = bsum[blockIdx.x] + sm[tid] - v;
    if (i == 0) rowp[M] = total;
}

__global__ void k_scatter(const int* __restrict__ ts, const int* __restrict__ td,
                          const int* __restrict__ rowp, int* __restrict__ cursor,
                          const float* __restrict__ rn,
                          int2* __restrict__ packed, int T) {
    int t = blockIdx.x * blockDim.x + threadIdx.x;
    if (t >= T) return;
    int a = ts[t], b = td[t];
    float d = rn[a * 3 + 0] * rn[b * 3 + 0]
            + rn[a * 3 + 1] * rn[b * 3 + 1]
            + rn[a * 3 + 2] * rn[b * 3 + 2];
    d = fminf(1.0f, fmaxf(-1.0f, d));
    int pos = rowp[b] + atomicAdd(&cursor[b], 1);
    packed[pos] = make_int2(a, __float_as_int(d));
}

__global__ void k_escatter(const int* __restrict__ gd, const int* __restrict__ erowp,
                           int* __restrict__ cursor, int* __restrict__ eord, int E) {
    int e = blockIdx.x * blockDim.x + threadIdx.x;
    if (e >= E) return;
    int n = gd[e];
    int pos = erowp[n] + atomicAdd(&cursor[n], 1);
    eord[pos] = e;
}

// 32x32 tiled transpose + cast: src fp32 [K][Nn] -> dst bf16 [Nn][K].
__global__ __launch_bounds__(256) void k_castT(
    const float* __restrict__ src, bf16_t* __restrict__ dst, int K, int Nn) {
    __shared__ float tile[32][33];
    int k0 = blockIdx.x * 32, n0 = blockIdx.y * 32;
    int tx = threadIdx.x & 31, ty = threadIdx.x >> 5;
    #pragma unroll
    for (int i = 0; i < 4; ++i) {
        int row = ty + i * 8;
        tile[row][tx] = src[(size_t)(k0 + row) * Nn + n0 + tx];
    }
    __syncthreads();
    #pragma unroll
    for (int i = 0; i < 4; ++i) {
        int row = ty + i * 8;
        dst[(size_t)(n0 + row) * K + k0 + tx] = f2bf(tile[tx][row]);
    }
}

// MFMA node_proj: xs = x@Wsrc + bs, xd = x@Wdst + bd (fp32 out).
__global__ __launch_bounds__(256) void k_node_proj(
    const bf16_t* __restrict__ xb,
    const bf16_t* __restrict__ Wst, const float* __restrict__ bs,
    const bf16_t* __restrict__ Wdt, const float* __restrict__ bd,
    float* __restrict__ xs, float* __restrict__ xd, int N) {
    int tid = threadIdx.x;
    int w = tid >> 6, lane = tid & 63;
    int col = lane & 15, quad = lane >> 4;
    int m0 = blockIdx.x * 64 + w * 16;
    f4 as[4] = {{0.f,0.f,0.f,0.f},{0.f,0.f,0.f,0.f},
                {0.f,0.f,0.f,0.f},{0.f,0.f,0.f,0.f}};
    f4 ad[4] = {{0.f,0.f,0.f,0.f},{0.f,0.f,0.f,0.f},
                {0.f,0.f,0.f,0.f},{0.f,0.f,0.f,0.f}};
    #pragma unroll
    for (int k0 = 0; k0 < DMODEL; k0 += 32) {
        s8v a = *(const s8v*)&xb[(size_t)(m0 + col) * DMODEL + k0 + quad * 8];
        #pragma unroll
        for (int t = 0; t < 4; ++t) {
            s8v b1v = *(const s8v*)&Wst[(size_t)(t * 16 + col) * DMODEL + k0 + quad * 8];
            as[t] = __builtin_amdgcn_mfma_f32_16x16x32_bf16(a, b1v, as[t], 0, 0, 0);
            s8v b2v = *(const s8v*)&Wdt[(size_t)(t * 16 + col) * DMODEL + k0 + quad * 8];
            ad[t] = __builtin_amdgcn_mfma_f32_16x16x32_bf16(a, b2v, ad[t], 0, 0, 0);
        }
    }
    #pragma unroll
    for (int t = 0; t < 4; ++t) {
        int c = t * 16 + col;
        float bsv = bs[c], bdv = bd[c];
        #pragma unroll
        for (int r = 0; r < 4; ++r) {
            int m = m0 + quad * 4 + r;
            if (m < N) {
                xs[(size_t)m * DM + c] = as[t][r] + bsv;
                xd[(size_t)m * DM + c] = ad[t][r] + bdv;
            }
        }
    }
}

// MFMA k_xij: xij[e][c] = (RBF(bl[e]) @ Wedge)[c] + xs[gs[e]][c] + xd[gd[e]][c] + be[c]
__global__ __launch_bounds__(256) void k_xij(
    const float* __restrict__ bl, const bf16_t* __restrict__ Wedgt,
    const float* __restrict__ be,
    const float* __restrict__ xs, const float* __restrict__ xd,
    const int* __restrict__ gs, const int* __restrict__ gd,
    bf16_t* __restrict__ xij, int E) {
    int tid = threadIdx.x;
    int w = tid >> 6, lane = tid & 63;
    int col = lane & 15, quad = lane >> 4;
    int m0 = blockIdx.x * 64 + w * 16;
    const float step = 8.0f / 255.0f;
    const float gamma = (255.0f / 8.0f) * (255.0f / 8.0f);
    int me = m0 + col;
    float blv = (me < E) ? bl[me] : 0.f;
    f4 acc[4] = {{0.f,0.f,0.f,0.f},{0.f,0.f,0.f,0.f},
                 {0.f,0.f,0.f,0.f},{0.f,0.f,0.f,0.f}};
    #pragma unroll
    for (int k0 = 0; k0 < DMODEL; k0 += 32) {
        s8v a;
        #pragma unroll
        for (int j = 0; j < 8; ++j) {
            float c = (float)(k0 + quad * 8 + j) * step;
            float dd = blv - c;
            a[j] = (short)f2bf(__expf(-gamma * dd * dd));
        }
        #pragma unroll
        for (int t = 0; t < 4; ++t) {
            s8v b = *(const s8v*)&Wedgt[(size_t)(t * 16 + col) * DMODEL + k0 + quad * 8];
            acc[t] = __builtin_amdgcn_mfma_f32_16x16x32_bf16(a, b, acc[t], 0, 0, 0);
        }
    }
    #pragma unroll
    for (int r = 0; r < 4; ++r) {
        int e = m0 + quad * 4 + r;
        if (e >= E) continue;
        int s = gs[e], d2 = gd[e];
        #pragma unroll
        for (int t = 0; t < 4; ++t) {
            int c = t * 16 + col;
            float v = acc[t][r] + xs[(size_t)s * DM + c] + xd[(size_t)d2 * DM + c] + be[c];
            xij[(size_t)e * DM + c] = f2bf(v);
        }
    }
}

// Fused logit+softmax+attend: 16-lane group per edge, lane q = channels
// [4q, 4q+4). Single pass over the segment; each src row gathered once.
// T_k(cos) via complex rotation: z = (c, sqrt(1-c^2)); z^{4q} by binary
// ladder; then 3 in-register rotations. Logit via 4-step __shfl_xor (within
// the 16-lane group); online softmax; bf16 msg store.
__global__ __launch_bounds__(256) void k_edge_attn(
    const bf16_t* __restrict__ xij, const int2* __restrict__ packed,
    const int* __restrict__ rowp, const float* __restrict__ attn_l,
    bf16_t* __restrict__ msg, int E) {
    int gtid = blockIdx.x * 256 + threadIdx.x;
    int e = gtid >> 4;
    if (e >= E) return;
    int q = gtid & 15;
    int beg = rowp[e], end = rowp[e + 1];
    float a0 = 0.f, a1 = 0.f, a2 = 0.f, a3 = 0.f;
    if (beg < end) {
        uint2 ue = *(const uint2*)&xij[(size_t)e * DM + q * 4];
        float xe0 = bf_lo(ue.x), xe1 = bf_hi(ue.x);
        float xe2 = bf_lo(ue.y), xe3 = bf_hi(ue.y);
        float4 at = *(const float4*)&attn_l[q * 4];
        float mrun = -1e30f, den = 0.f;
        for (int p = beg; p < end; ++p) {
            int2 pk = packed[p];
            int s = pk.x;
            float cth = __int_as_float(pk.y);
            float sth = sqrtf(fmaxf(0.f, 1.f - cth * cth));
            // src row quad (the single gather)
            uint2 us = *(const uint2*)&xij[(size_t)s * DM + q * 4];
            float xs0 = bf_lo(us.x), xs1 = bf_hi(us.x);
            float xs2 = bf_lo(us.y), xs3 = bf_hi(us.y);
            // z^4
            float br = cth, bi = sth;
            { float t = br*br - bi*bi; bi = 2.f*br*bi; br = t; }
            { float t = br*br - bi*bi; bi = 2.f*br*bi; br = t; }
            // (z^4)^q via 4-bit ladder
            float pr = 1.f, pi = 0.f;
            int mm = q;
            #pragma unroll
            for (int it = 0; it < 4; ++it) {
                if (mm & 1) { float t = pr*br - pi*bi; pi = pr*bi + pi*br; pr = t; }
                mm >>= 1;
                if (it < 3) { float t = br*br - bi*bi; bi = 2.f*br*bi; br = t; }
            }
            // channels 4q..4q+3: T_k = Re, rotate by z each step
            float tr = pr, ti = pi;
            float partial;
            {
                float u0 = tr + xs0 + xe0;
                { float t = tr*cth - ti*sth; ti = tr*sth + ti*cth; tr = t; }
                float u1 = tr + xs1 + xe1;
                { float t = tr*cth - ti*sth; ti = tr*sth + ti*cth; tr = t; }
                float u2 = tr + xs2 + xe2;
                { float t = tr*cth - ti*sth; ti = tr*sth + ti*cth; tr = t; }
                float u3 = tr + xs3 + xe3;
                float s0 = u0 / (1.f + __expf(-u0));
                float s1 = u1 / (1.f + __expf(-u1));
                float s2 = u2 / (1.f + __expf(-u2));
                float s3 = u3 / (1.f + __expf(-u3));
                partial = fmaf(s0, at.x, fmaf(s1, at.y,
                          fmaf(s2, at.z, s3 * at.w)));
            }
            // logit = sum over the 16-lane group
            #pragma unroll
            for (int off = 1; off < 16; off <<= 1)
                partial += __shfl_xor(partial, off, 64);
            // online softmax update (uniform across the group)
            float nm = fmaxf(mrun, partial);
            float sc = __expf(mrun - nm);
            float wg = __expf(partial - nm);
            den = den * sc + wg;
            a0 = fmaf(wg, xs0, a0 * sc);
            a1 = fmaf(wg, xs1, a1 * sc);
            a2 = fmaf(wg, xs2, a2 * sc);
            a3 = fmaf(wg, xs3, a3 * sc);
            mrun = nm;
        }
        float inv = 1.f / den;
        a0 *= inv; a1 *= inv; a2 *= inv; a3 *= inv;
    }
    ushort4 o = {f2bf(a0), f2bf(a1), f2bf(a2), f2bf(a3)};
    *(ushort4*)&msg[(size_t)e * DM + q * 4] = o;
}

// thread per (node, channel-quad): sum bf16 msg -> bf16 ft.
__global__ __launch_bounds__(256) void k_aggregate(
    const bf16_t* __restrict__ msg, const int* __restrict__ erowp,
    const int* __restrict__ eord, bf16_t* __restrict__ ft, int N) {
    int gtid = blockIdx.x * 256 + threadIdx.x;
    int n = gtid >> 4;
    if (n >= N) return;
    int quad = gtid & 15;
    int beg = erowp[n], end = erowp[n + 1];
    float a0 = 0.f, a1 = 0.f, a2 = 0.f, a3 = 0.f;
    for (int j = beg; j < end; ++j) {
        uint2 uv = *(const uint2*)&msg[(size_t)eord[j] * DM + quad * 4];
        a0 += bf_lo(uv.x); a1 += bf_hi(uv.x);
        a2 += bf_lo(uv.y); a3 += bf_hi(uv.y);
    }
    ushort4 o = {f2bf(a0), f2bf(a1), f2bf(a2), f2bf(a3)};
    *(ushort4*)&ft[(size_t)n * DM + quad * 4] = o;
}

// MFMA ffn1: h = silu(ft(bf16) @ W1 + b1), h bf16. grid (157, 16).
__global__ __launch_bounds__(256) void k_ffn1(
    const bf16_t* __restrict__ ft, const bf16_t* __restrict__ W1t,
    const float* __restrict__ b1, bf16_t* __restrict__ h, int N) {
    int tid = threadIdx.x;
    int w = tid >> 6, lane = tid & 63;
    int col = lane & 15, quad = lane >> 4;
    int m0 = blockIdx.x * 64 + w * 16;
    int c0 = blockIdx.y * 64;
    f4 acc[4] = {{0.f,0.f,0.f,0.f},{0.f,0.f,0.f,0.f},
                 {0.f,0.f,0.f,0.f},{0.f,0.f,0.f,0.f}};
    #pragma unroll
    for (int k0 = 0; k0 < DM; k0 += 32) {
        s8v a = *(const s8v*)&ft[(size_t)(m0 + col) * DM + k0 + quad * 8];
        #pragma unroll
        for (int t = 0; t < 4; ++t) {
            s8v b = *(const s8v*)&W1t[(size_t)(c0 + t * 16 + col) * DM + k0 + quad * 8];
            acc[t] = __builtin_amdgcn_mfma_f32_16x16x32_bf16(a, b, acc[t], 0, 0, 0);
        }
    }
    #pragma unroll
    for (int t = 0; t < 4; ++t) {
        int c = c0 + t * 16 + col;
        float bb = b1[c];
        #pragma unroll
        for (int r = 0; r < 4; ++r) {
            int m = m0 + quad * 4 + r;
            if (m < N) {
                float v = acc[t][r] + bb;
                h[(size_t)m * HDIM + c] = f2bf(v / (1.0f + __expf(-v)));
            }
        }
    }
}

// MFMA ffn2: x = h(bf16) @ W2 + b2 (bf16 out). grid (157, 4).
__global__ __launch_bounds__(256) void k_ffn2(
    const bf16_t* __restrict__ h, const bf16_t* __restrict__ W2t,
    const float* __restrict__ b2, bf16_t* __restrict__ x, int N) {
    int tid = threadIdx.x;
    int w = tid >> 6, lane = tid & 63;
    int col = lane & 15, quad = lane >> 4;
    int m0 = blockIdx.x * 64 + w * 16;
    int c0 = blockIdx.y * 64;
    f4 acc[4] = {{0.f,0.f,0.f,0.f},{0.f,0.f,0.f,0.f},
                 {0.f,0.f,0.f,0.f},{0.f,0.f,0.f,0.f}};
    for (int k0 = 0; k0 < HDIM; k0 += 32) {
        s8v a = *(const s8v*)&h[(size_t)(m0 + col) * HDIM + k0 + quad * 8];
        #pragma unroll
        for (int t = 0; t < 4; ++t) {
            s8v b = *(const s8v*)&W2t[(size_t)(c0 + t * 16 + col) * HDIM + k0 + quad * 8];
            acc[t] = __builtin_amdgcn_mfma_f32_16x16x32_bf16(a, b, acc[t], 0, 0, 0);
        }
    }
    #pragma unroll
    for (int t = 0; t < 4; ++t) {
        int c = c0 + t * 16 + col;
        float bb = b2[c];
        #pragma unroll
        for (int r = 0; r < 4; ++r) {
            int m = m0 + quad * 4 + r;
            if (m < N) x[(size_t)m * DMODEL + c] = f2bf(acc[t][r] + bb);
        }
    }
}

// grid-stride dot over bf16 x, one atomic per block.
__global__ __launch_bounds__(256) void k_out_reduce(
    const bf16_t* __restrict__ x, const float* __restrict__ Wfc,
    float* __restrict__ acc, int NT) {
    __shared__ float sm[4];
    int tid = threadIdx.x;
    float v = 0.f;
    int np = NT / 2;
    const unsigned int* xp = (const unsigned int*)x;
    for (int i = blockIdx.x * blockDim.x + tid; i < np; i += gridDim.x * blockDim.x) {
        unsigned int u = xp[i];
        int c = (2 * i) & (DMODEL - 1);
        v = fmaf(bf_lo(u), Wfc[c], v);
        v = fmaf(bf_hi(u), Wfc[c + 1], v);
    }
    for (int off = 32; off > 0; off >>= 1) v += __shfl_xor(v, off, 64);
    if ((tid & 63) == 0) sm[tid >> 6] = v;
    __syncthreads();
    if (tid == 0) {
        float s = sm[0] + sm[1] + sm[2] + sm[3];
        atomicAdd(acc, s);
    }
}

__global__ void k_out_final(const float* __restrict__ acc, const float* __restrict__ bfc,
                            float* __restrict__ out, float invN) {
    out[0] = acc[0] * invN + bfc[0];
}

extern "C" void kernel_launch(void* const* d_in, const int* in_sizes, int n_in,
                              void* d_out, int out_size, void* d_ws, size_t ws_size,
                              hipStream_t stream) {
    const int*   an    = (const int*)d_in[0];
    const int*   gs    = (const int*)d_in[1];
    const int*   gd    = (const int*)d_in[2];
    const int*   ts    = (const int*)d_in[3];
    const int*   td    = (const int*)d_in[4];
    const float* r     = (const float*)d_in[5];
    const float* emb   = (const float*)d_in[6];
    const float* Wsrc  = (const float*)d_in[7];
    const float* bsrc  = (const float*)d_in[8];
    const float* Wdst  = (const float*)d_in[9];
    const float* bdst  = (const float*)d_in[10];
    const float* Wedge = (const float*)d_in[11];
    const float* bedge = (const float*)d_in[12];
    const float* attn  = (const float*)d_in[13];
    const float* W1    = (const float*)d_in[14];
    const float* b1    = (const float*)d_in[15];
    const float* W2    = (const float*)d_in[16];
    const float* b2    = (const float*)d_in[17];
    const float* Wfc   = (const float*)d_in[18];
    const float* bfc   = (const float*)d_in[19];

    const int N = in_sizes[0];
    const int E = in_sizes[1];
    const int T = in_sizes[3];

    char* w = (char*)d_ws;
    size_t off = 0;
    auto alloc = [&](size_t bytes) {
        void* p = w + off;
        off += (bytes + 255) & ~(size_t)255;
        return p;
    };
    bf16_t* xb     = (bf16_t*)alloc((size_t)(N + 64) * DMODEL * 2);
    float*  rn     = (float*) alloc((size_t)E * 3 * 4);
    float*  bl     = (float*) alloc(((size_t)E + 64) * 4);
    int*    cnt    = (int*)   alloc((size_t)E * 4);
    int*    rowp   = (int*)   alloc(((size_t)E + 1) * 4);
    int*    bsum   = (int*)   alloc(4096);
    int2*   packed = (int2*)  alloc((size_t)T * 8);
    int*    ecnt   = (int*)   alloc((size_t)N * 4);
    int*    erowp  = (int*)   alloc(((size_t)N + 1) * 4);
    int*    eord   = (int*)   alloc((size_t)E * 4);
    float*  xs     = (float*) alloc((size_t)N * DM * 4);
    float*  xd     = (float*) alloc((size_t)N * DM * 4);
    bf16_t* xij    = (bf16_t*)alloc((size_t)E * DM * 2);
    bf16_t* msg    = (bf16_t*)alloc((size_t)E * DM * 2);
    bf16_t* ft     = (bf16_t*)alloc((size_t)(N + 64) * DM * 2);
    bf16_t* hb     = (bf16_t*)alloc((size_t)(N + 64) * HDIM * 2);
    bf16_t* W1t    = (bf16_t*)alloc((size_t)3 * HDIM * DM * 2);
    bf16_t* W2t    = (bf16_t*)alloc((size_t)3 * DMODEL * HDIM * 2);
    bf16_t* Wedgt  = (bf16_t*)alloc((size_t)3 * DM * DMODEL * 2);
    bf16_t* Wst    = (bf16_t*)alloc((size_t)3 * DM * DMODEL * 2);
    bf16_t* Wdt    = (bf16_t*)alloc((size_t)3 * DM * DMODEL * 2);
    float*  accs   = (float*) alloc(64);
    (void)ws_size; (void)n_in; (void)out_size;

    const int nbScanE = (E + 255) / 256;
    const int nbScanN = (N + 255) / 256;

    // ---- setup (layer-invariant) ----
    k_embed<<<N, 256, 0, stream>>>(an, emb, xb);
    k_edge_geom<<<(E + 255) / 256, 256, 0, stream>>>(r, bl, rn, E);
    for (int l = 0; l < 3; ++l) {
        k_castT<<<dim3(DM / 32, HDIM / 32), 256, 0, stream>>>(
            W1 + (size_t)l * DM * HDIM, W1t + (size_t)l * HDIM * DM, DM, HDIM);
        k_castT<<<dim3(HDIM / 32, DMODEL / 32), 256, 0, stream>>>(
            W2 + (size_t)l * HDIM * DMODEL, W2t + (size_t)l * DMODEL * HDIM,
            HDIM, DMODEL);
        k_castT<<<dim3(DMODEL / 32, DM / 32), 256, 0, stream>>>(
            Wedge + (size_t)l * DMODEL * DM, Wedgt + (size_t)l * DM * DMODEL,
            DMODEL, DM);
        k_castT<<<dim3(DMODEL / 32, DM / 32), 256, 0, stream>>>(
            Wsrc + (size_t)l * DMODEL * DM, Wst + (size_t)l * DM * DMODEL,
            DMODEL, DM);
        k_castT<<<dim3(DMODEL / 32, DM / 32), 256, 0, stream>>>(
            Wdst + (size_t)l * DMODEL * DM, Wdt + (size_t)l * DM * DMODEL,
            DMODEL, DM);
    }
    // triplet CSR by t_dst
    hipMemsetAsync(cnt, 0, (size_t)E * 4, stream);
    k_hist<<<(T + 255) / 256, 256, 0, stream>>>(td, cnt, T);
    k_scan_part<<<nbScanE, 256, 0, stream>>>(cnt, bsum, E);
    k_scan_mid<<<1, 1024, 0, stream>>>(bsum, nbScanE);
    k_scan_final<<<nbScanE, 256, 0, stream>>>(cnt, bsum, rowp, E, T);
    hipMemsetAsync(cnt, 0, (size_t)E * 4, stream);
    k_scatter<<<(T + 255) / 256, 256, 0, stream>>>(ts, td, rowp, cnt, rn,
                                                   packed, T);
    // edge CSR by gd
    hipMemsetAsync(ecnt, 0, (size_t)N * 4, stream);
    k_hist<<<(E + 255) / 256, 256, 0, stream>>>(gd, ecnt, E);
    k_scan_part<<<nbScanN, 256, 0, stream>>>(ecnt, bsum, N);
    k_scan_mid<<<1, 1024, 0, stream>>>(bsum, nbScanN);
    k_scan_final<<<nbScanN, 256, 0, stream>>>(ecnt, bsum, erowp, N, E);
    hipMemsetAsync(ecnt, 0, (size_t)N * 4, stream);
    k_escatter<<<(E + 255) / 256, 256, 0, stream>>>(gd, erowp, ecnt, eord, E);

    // ---- layers ----
    for (int l = 0; l < 3; ++l) {
        k_node_proj<<<(N + 63) / 64, 256, 0, stream>>>(
            xb, Wst + (size_t)l * DM * DMODEL, bsrc + l * DM,
            Wdt + (size_t)l * DM * DMODEL, bdst + l * DM, xs, xd, N);
        k_xij<<<(E + 63) / 64, 256, 0, stream>>>(
            bl, Wedgt + (size_t)l * DM * DMODEL, bedge + l * DM,
            xs, xd, gs, gd, xij, E);
        k_edge_attn<<<(E * 16 + 255) / 256, 256, 0, stream>>>(
            xij, packed, rowp, attn + l * DM, msg, E);
        k_aggregate<<<(N * 16 + 255) / 256, 256, 0, stream>>>(
            msg, erowp, eord, ft, N);
        k_ffn1<<<dim3((N + 63) / 64, HDIM / 64), 256, 0, stream>>>(
            ft, W1t + (size_t)l * HDIM * DM, b1 + l * HDIM, hb, N);
        k_ffn2<<<dim3((N + 63) / 64, DMODEL / 64), 256, 0, stream>>>(
            hb, W2t + (size_t)l * DMODEL * HDIM, b2 + l * DMODEL, xb, N);
    }

    // ---- output head ----
    hipMemsetAsync(accs, 0, 4, stream);
    k_out_reduce<<<120, 256, 0, stream>>>(xb, Wfc, accs, N * DMODEL);
    k_out_final<<<1, 1, 0, stream>>>(accs, bfc, (float*)d_out, 1.0f / (float)N);
}

// Round 14
// 1008.293 us; speedup vs baseline: 1.5801x; 1.0785x over previous
//
#include <hip/hip_runtime.h>
#include <math.h>

// M3GNet-like GNN forward. N=10000 nodes, E=160000 edges, T=1200000 triplets,
// D=256, DM=64, H=1024, L=3, output = scalar mean energy (fp32).
//
// R13: k_edge_attn VALU diet (was VALUBusy ~106%, 122 us/layer):
//  - packed stores theta (acos in one-time k_scatter); T_k = __cosf(k*theta)
//    -> 4 quarter-rate cos vs ~60-op divergent complex-rotation ladder.
//  - softmax without running-max (logits bounded ~|40|, exp safe in fp32)
//    -> removes the serial rescale chain; accumulations pipeline freely.

#define DM 64
#define DMODEL 256
#define HDIM 1024

typedef unsigned short bf16_t;
typedef __attribute__((ext_vector_type(8))) short s8v;    // 8 bf16 (4 VGPRs)
typedef __attribute__((ext_vector_type(4))) float f4;     // MFMA acc

__device__ __forceinline__ bf16_t f2bf(float f) {
    unsigned int u = __float_as_uint(f);
    return (bf16_t)((u + 0x7FFFu + ((u >> 16) & 1u)) >> 16);   // RNE
}
__device__ __forceinline__ float bf_lo(unsigned int u) {
    return __uint_as_float(u << 16);
}
__device__ __forceinline__ float bf_hi(unsigned int u) {
    return __uint_as_float(u & 0xFFFF0000u);
}

__global__ void k_embed(const int* __restrict__ an, const float* __restrict__ emb,
                        bf16_t* __restrict__ x) {
    int n = blockIdx.x;
    int d = threadIdx.x;
    x[n * DMODEL + d] = f2bf(emb[an[n] * DMODEL + d]);
}

__global__ void k_edge_geom(const float* __restrict__ r, float* __restrict__ bl,
                            float* __restrict__ rn, int E) {
    int e = blockIdx.x * blockDim.x + threadIdx.x;
    if (e >= E) return;
    float a = r[e * 3 + 0], b = r[e * 3 + 1], c = r[e * 3 + 2];
    float l = sqrtf(a * a + b * b + c * c);
    bl[e] = l;
    float inv = 1.0f / l;
    rn[e * 3 + 0] = a * inv;
    rn[e * 3 + 1] = b * inv;
    rn[e * 3 + 2] = c * inv;
}

__global__ void k_hist(const int* __restrict__ idx, int* __restrict__ cnt, int M) {
    int t = blockIdx.x * blockDim.x + threadIdx.x;
    if (t < M) atomicAdd(&cnt[idx[t]], 1);
}

// ---- 3-phase exclusive scan ----
__global__ __launch_bounds__(256) void k_scan_part(
    const int* __restrict__ cnt, int* __restrict__ bsum, int M) {
    __shared__ int sm[4];
    int tid = threadIdx.x;
    int i = blockIdx.x * 256 + tid;
    int v = (i < M) ? cnt[i] : 0;
    for (int off = 32; off > 0; off >>= 1) v += __shfl_xor(v, off, 64);
    if ((tid & 63) == 0) sm[tid >> 6] = v;
    __syncthreads();
    if (tid == 0) bsum[blockIdx.x] = sm[0] + sm[1] + sm[2] + sm[3];
}

__global__ __launch_bounds__(1024) void k_scan_mid(int* __restrict__ bsum, int nb) {
    __shared__ int sm[1024];
    int tid = threadIdx.x;
    int v = (tid < nb) ? bsum[tid] : 0;
    sm[tid] = v;
    __syncthreads();
    for (int off = 1; off < 1024; off <<= 1) {
        int u = (tid >= off) ? sm[tid - off] : 0;
        __syncthreads();
        sm[tid] += u;
        __syncthreads();
    }
    if (tid < nb) bsum[tid] = sm[tid] - v;
}

__global__ __launch_bounds__(256) void k_scan_final(
    const int* __restrict__ cnt, const int* __restrict__ bsum,
    int* __restrict__ rowp, int M, int total) {
    __shared__ int sm[256];
    int tid = threadIdx.x;
    int i = blockIdx.x * 256 + tid;
    int v = (i < M) ? cnt[i] : 0;
    sm[tid] = v;
    __syncthreads();
    for (int off = 1; off < 256; off <<= 1) {
        int u = (tid >= off) ? sm[tid - off] : 0;
        __syncthreads();
        sm[tid] += u;
        __syncthreads();
    }
    if (i < M) rowp[i] = bsum[blockIdx.x] + sm[tid] - v;
    if (i == 0) rowp[M] = total;
}

// scatter triplets into segment order; packed = (src, theta-bits).
__global__ void k_scatter(const int* __restrict__ ts, const int* __restrict__ td,
                          const int* __restrict__ rowp, int* __restrict__ cursor,
                          const float* __restrict__ rn,
                          int2* __restrict__ packed, int T) {
    int t = blockIdx.x * blockDim.x + threadIdx.x;
    if (t >= T) return;
    int a = ts[t], b = td[t];
    float d = rn[a * 3 + 0] * rn[b * 3 + 0]
            + rn[a * 3 + 1] * rn[b * 3 + 1]
            + rn[a * 3 + 2] * rn[b * 3 + 2];
    d = fminf(1.0f, fmaxf(-1.0f, d));
    float th = acosf(d);
    int pos = rowp[b] + atomicAdd(&cursor[b], 1);
    packed[pos] = make_int2(a, __float_as_int(th));
}

__global__ void k_escatter(const int* __restrict__ gd, const int* __restrict__ erowp,
                           int* __restrict__ cursor, int* __restrict__ eord, int E) {
    int e = blockIdx.x * blockDim.x + threadIdx.x;
    if (e >= E) return;
    int n = gd[e];
    int pos = erowp[n] + atomicAdd(&cursor[n], 1);
    eord[pos] = e;
}

// 32x32 tiled transpose + cast: src fp32 [K][Nn] -> dst bf16 [Nn][K].
__global__ __launch_bounds__(256) void k_castT(
    const float* __restrict__ src, bf16_t* __restrict__ dst, int K, int Nn) {
    __shared__ float tile[32][33];
    int k0 = blockIdx.x * 32, n0 = blockIdx.y * 32;
    int tx = threadIdx.x & 31, ty = threadIdx.x >> 5;
    #pragma unroll
    for (int i = 0; i < 4; ++i) {
        int row = ty + i * 8;
        tile[row][tx] = src[(size_t)(k0 + row) * Nn + n0 + tx];
    }
    __syncthreads();
    #pragma unroll
    for (int i = 0; i < 4; ++i) {
        int row = ty + i * 8;
        dst[(size_t)(n0 + row) * K + k0 + tx] = f2bf(tile[tx][row]);
    }
}

// MFMA node_proj: xs = x@Wsrc + bs, xd = x@Wdst + bd (fp32 out).
__global__ __launch_bounds__(256) void k_node_proj(
    const bf16_t* __restrict__ xb,
    const bf16_t* __restrict__ Wst, const float* __restrict__ bs,
    const bf16_t* __restrict__ Wdt, const float* __restrict__ bd,
    float* __restrict__ xs, float* __restrict__ xd, int N) {
    int tid = threadIdx.x;
    int w = tid >> 6, lane = tid & 63;
    int col = lane & 15, quad = lane >> 4;
    int m0 = blockIdx.x * 64 + w * 16;
    f4 as[4] = {{0.f,0.f,0.f,0.f},{0.f,0.f,0.f,0.f},
                {0.f,0.f,0.f,0.f},{0.f,0.f,0.f,0.f}};
    f4 ad[4] = {{0.f,0.f,0.f,0.f},{0.f,0.f,0.f,0.f},
                {0.f,0.f,0.f,0.f},{0.f,0.f,0.f,0.f}};
    #pragma unroll
    for (int k0 = 0; k0 < DMODEL; k0 += 32) {
        s8v a = *(const s8v*)&xb[(size_t)(m0 + col) * DMODEL + k0 + quad * 8];
        #pragma unroll
        for (int t = 0; t < 4; ++t) {
            s8v b1v = *(const s8v*)&Wst[(size_t)(t * 16 + col) * DMODEL + k0 + quad * 8];
            as[t] = __builtin_amdgcn_mfma_f32_16x16x32_bf16(a, b1v, as[t], 0, 0, 0);
            s8v b2v = *(const s8v*)&Wdt[(size_t)(t * 16 + col) * DMODEL + k0 + quad * 8];
            ad[t] = __builtin_amdgcn_mfma_f32_16x16x32_bf16(a, b2v, ad[t], 0, 0, 0);
        }
    }
    #pragma unroll
    for (int t = 0; t < 4; ++t) {
        int c = t * 16 + col;
        float bsv = bs[c], bdv = bd[c];
        #pragma unroll
        for (int r = 0; r < 4; ++r) {
            int m = m0 + quad * 4 + r;
            if (m < N) {
                xs[(size_t)m * DM + c] = as[t][r] + bsv;
                xd[(size_t)m * DM + c] = ad[t][r] + bdv;
            }
        }
    }
}

// MFMA k_xij: xij[e][c] = (RBF(bl[e]) @ Wedge)[c] + xs[gs[e]][c] + xd[gd[e]][c] + be[c]
__global__ __launch_bounds__(256) void k_xij(
    const float* __restrict__ bl, const bf16_t* __restrict__ Wedgt,
    const float* __restrict__ be,
    const float* __restrict__ xs, const float* __restrict__ xd,
    const int* __restrict__ gs, const int* __restrict__ gd,
    bf16_t* __restrict__ xij, int E) {
    int tid = threadIdx.x;
    int w = tid >> 6, lane = tid & 63;
    int col = lane & 15, quad = lane >> 4;
    int m0 = blockIdx.x * 64 + w * 16;
    const float step = 8.0f / 255.0f;
    const float gamma = (255.0f / 8.0f) * (255.0f / 8.0f);
    int me = m0 + col;
    float blv = (me < E) ? bl[me] : 0.f;
    f4 acc[4] = {{0.f,0.f,0.f,0.f},{0.f,0.f,0.f,0.f},
                 {0.f,0.f,0.f,0.f},{0.f,0.f,0.f,0.f}};
    #pragma unroll
    for (int k0 = 0; k0 < DMODEL; k0 += 32) {
        s8v a;
        #pragma unroll
        for (int j = 0; j < 8; ++j) {
            float c = (float)(k0 + quad * 8 + j) * step;
            float dd = blv - c;
            a[j] = (short)f2bf(__expf(-gamma * dd * dd));
        }
        #pragma unroll
        for (int t = 0; t < 4; ++t) {
            s8v b = *(const s8v*)&Wedgt[(size_t)(t * 16 + col) * DMODEL + k0 + quad * 8];
            acc[t] = __builtin_amdgcn_mfma_f32_16x16x32_bf16(a, b, acc[t], 0, 0, 0);
        }
    }
    #pragma unroll
    for (int r = 0; r < 4; ++r) {
        int e = m0 + quad * 4 + r;
        if (e >= E) continue;
        int s = gs[e], d2 = gd[e];
        #pragma unroll
        for (int t = 0; t < 4; ++t) {
            int c = t * 16 + col;
            float v = acc[t][r] + xs[(size_t)s * DM + c] + xd[(size_t)d2 * DM + c] + be[c];
            xij[(size_t)e * DM + c] = f2bf(v);
        }
    }
}

// Fused logit+softmax+attend: 16-lane group per edge, lane q = channels
// [4q, 4q+4). T_k = __cosf(k*theta). No running max (logits bounded).
__global__ __launch_bounds__(256) void k_edge_attn(
    const bf16_t* __restrict__ xij, const int2* __restrict__ packed,
    const int* __restrict__ rowp, const float* __restrict__ attn_l,
    bf16_t* __restrict__ msg, int E) {
    int gtid = blockIdx.x * 256 + threadIdx.x;
    int e = gtid >> 4;
    if (e >= E) return;
    int q = gtid & 15;
    int beg = rowp[e], end = rowp[e + 1];
    float a0 = 0.f, a1 = 0.f, a2 = 0.f, a3 = 0.f;
    if (beg < end) {
        uint2 ue = *(const uint2*)&xij[(size_t)e * DM + q * 4];
        float xe0 = bf_lo(ue.x), xe1 = bf_hi(ue.x);
        float xe2 = bf_lo(ue.y), xe3 = bf_hi(ue.y);
        float4 at = *(const float4*)&attn_l[q * 4];
        float kf = (float)(4 * q);
        float den = 0.f;
        for (int p = beg; p < end; ++p) {
            int2 pk = packed[p];
            int s = pk.x;
            float th = __int_as_float(pk.y);
            uint2 us = *(const uint2*)&xij[(size_t)s * DM + q * 4];
            float xs0 = bf_lo(us.x), xs1 = bf_hi(us.x);
            float xs2 = bf_lo(us.y), xs3 = bf_hi(us.y);
            float u0 = __cosf(kf * th) + xs0 + xe0;
            float u1 = __cosf((kf + 1.f) * th) + xs1 + xe1;
            float u2 = __cosf((kf + 2.f) * th) + xs2 + xe2;
            float u3 = __cosf((kf + 3.f) * th) + xs3 + xe3;
            float s0 = u0 / (1.f + __expf(-u0));
            float s1 = u1 / (1.f + __expf(-u1));
            float s2 = u2 / (1.f + __expf(-u2));
            float s3 = u3 / (1.f + __expf(-u3));
            float partial = fmaf(s0, at.x, fmaf(s1, at.y,
                            fmaf(s2, at.z, s3 * at.w)));
            #pragma unroll
            for (int off = 1; off < 16; off <<= 1)
                partial += __shfl_xor(partial, off, 64);
            float wg = __expf(partial);
            den += wg;
            a0 = fmaf(wg, xs0, a0);
            a1 = fmaf(wg, xs1, a1);
            a2 = fmaf(wg, xs2, a2);
            a3 = fmaf(wg, xs3, a3);
        }
        float inv = 1.f / den;
        a0 *= inv; a1 *= inv; a2 *= inv; a3 *= inv;
    }
    ushort4 o = {f2bf(a0), f2bf(a1), f2bf(a2), f2bf(a3)};
    *(ushort4*)&msg[(size_t)e * DM + q * 4] = o;
}

// thread per (node, channel-quad): sum bf16 msg -> bf16 ft.
__global__ __launch_bounds__(256) void k_aggregate(
    const bf16_t* __restrict__ msg, const int* __restrict__ erowp,
    const int* __restrict__ eord, bf16_t* __restrict__ ft, int N) {
    int gtid = blockIdx.x * 256 + threadIdx.x;
    int n = gtid >> 4;
    if (n >= N) return;
    int quad = gtid & 15;
    int beg = erowp[n], end = erowp[n + 1];
    float a0 = 0.f, a1 = 0.f, a2 = 0.f, a3 = 0.f;
    for (int j = beg; j < end; ++j) {
        uint2 uv = *(const uint2*)&msg[(size_t)eord[j] * DM + quad * 4];
        a0 += bf_lo(uv.x); a1 += bf_hi(uv.x);
        a2 += bf_lo(uv.y); a3 += bf_hi(uv.y);
    }
    ushort4 o = {f2bf(a0), f2bf(a1), f2bf(a2), f2bf(a3)};
    *(ushort4*)&ft[(size_t)n * DM + quad * 4] = o;
}

// MFMA ffn1: h = silu(ft(bf16) @ W1 + b1), h bf16. grid (157, 16).
__global__ __launch_bounds__(256) void k_ffn1(
    const bf16_t* __restrict__ ft, const bf16_t* __restrict__ W1t,
    const float* __restrict__ b1, bf16_t* __restrict__ h, int N) {
    int tid = threadIdx.x;
    int w = tid >> 6, lane = tid & 63;
    int col = lane & 15, quad = lane >> 4;
    int m0 = blockIdx.x * 64 + w * 16;
    int c0 = blockIdx.y * 64;
    f4 acc[4] = {{0.f,0.f,0.f,0.f},{0.f,0.f,0.f,0.f},
                 {0.f,0.f,0.f,0.f},{0.f,0.f,0.f,0.f}};
    #pragma unroll
    for (int k0 = 0; k0 < DM; k0 += 32) {
        s8v a = *(const s8v*)&ft[(size_t)(m0 + col) * DM + k0 + quad * 8];
        #pragma unroll
        for (int t = 0; t < 4; ++t) {
            s8v b = *(const s8v*)&W1t[(size_t)(c0 + t * 16 + col) * DM + k0 + quad * 8];
            acc[t] = __builtin_amdgcn_mfma_f32_16x16x32_bf16(a, b, acc[t], 0, 0, 0);
        }
    }
    #pragma unroll
    for (int t = 0; t < 4; ++t) {
        int c = c0 + t * 16 + col;
        float bb = b1[c];
        #pragma unroll
        for (int r = 0; r < 4; ++r) {
            int m = m0 + quad * 4 + r;
            if (m < N) {
                float v = acc[t][r] + bb;
                h[(size_t)m * HDIM + c] = f2bf(v / (1.0f + __expf(-v)));
            }
        }
    }
}

// MFMA ffn2: x = h(bf16) @ W2 + b2 (bf16 out). grid (157, 4).
__global__ __launch_bounds__(256) void k_ffn2(
    const bf16_t* __restrict__ h, const bf16_t* __restrict__ W2t,
    const float* __restrict__ b2, bf16_t* __restrict__ x, int N) {
    int tid = threadIdx.x;
    int w = tid >> 6, lane = tid & 63;
    int col = lane & 15, quad = lane >> 4;
    int m0 = blockIdx.x * 64 + w * 16;
    int c0 = blockIdx.y * 64;
    f4 acc[4] = {{0.f,0.f,0.f,0.f},{0.f,0.f,0.f,0.f},
                 {0.f,0.f,0.f,0.f},{0.f,0.f,0.f,0.f}};
    for (int k0 = 0; k0 < HDIM; k0 += 32) {
        s8v a = *(const s8v*)&h[(size_t)(m0 + col) * HDIM + k0 + quad * 8];
        #pragma unroll
        for (int t = 0; t < 4; ++t) {
            s8v b = *(const s8v*)&W2t[(size_t)(c0 + t * 16 + col) * HDIM + k0 + quad * 8];
            acc[t] = __builtin_amdgcn_mfma_f32_16x16x32_bf16(a, b, acc[t], 0, 0, 0);
        }
    }
    #pragma unroll
    for (int t = 0; t < 4; ++t) {
        int c = c0 + t * 16 + col;
        float bb = b2[c];
        #pragma unroll
        for (int r = 0; r < 4; ++r) {
            int m = m0 + quad * 4 + r;
            if (m < N) x[(size_t)m * DMODEL + c] = f2bf(acc[t][r] + bb);
        }
    }
}

// grid-stride dot over bf16 x, one atomic per block.
__global__ __launch_bounds__(256) void k_out_reduce(
    const bf16_t* __restrict__ x, const float* __restrict__ Wfc,
    float* __restrict__ acc, int NT) {
    __shared__ float sm[4];
    int tid = threadIdx.x;
    float v = 0.f;
    int np = NT / 2;
    const unsigned int* xp = (const unsigned int*)x;
    for (int i = blockIdx.x * blockDim.x + tid; i < np; i += gridDim.x * blockDim.x) {
        unsigned int u = xp[i];
        int c = (2 * i) & (DMODEL - 1);
        v = fmaf(bf_lo(u), Wfc[c], v);
        v = fmaf(bf_hi(u), Wfc[c + 1], v);
    }
    for (int off = 32; off > 0; off >>= 1) v += __shfl_xor(v, off, 64);
    if ((tid & 63) == 0) sm[tid >> 6] = v;
    __syncthreads();
    if (tid == 0) {
        float s = sm[0] + sm[1] + sm[2] + sm[3];
        atomicAdd(acc, s);
    }
}

__global__ void k_out_final(const float* __restrict__ acc, const float* __restrict__ bfc,
                            float* __restrict__ out, float invN) {
    out[0] = acc[0] * invN + bfc[0];
}

extern "C" void kernel_launch(void* const* d_in, const int* in_sizes, int n_in,
                              void* d_out, int out_size, void* d_ws, size_t ws_size,
                              hipStream_t stream) {
    const int*   an    = (const int*)d_in[0];
    const int*   gs    = (const int*)d_in[1];
    const int*   gd    = (const int*)d_in[2];
    const int*   ts    = (const int*)d_in[3];
    const int*   td    = (const int*)d_in[4];
    const float* r     = (const float*)d_in[5];
    const float* emb   = (const float*)d_in[6];
    const float* Wsrc  = (const float*)d_in[7];
    const float* bsrc  = (const float*)d_in[8];
    const float* Wdst  = (const float*)d_in[9];
    const float* bdst  = (const float*)d_in[10];
    const float* Wedge = (const float*)d_in[11];
    const float* bedge = (const float*)d_in[12];
    const float* attn  = (const float*)d_in[13];
    const float* W1    = (const float*)d_in[14];
    const float* b1    = (const float*)d_in[15];
    const float* W2    = (const float*)d_in[16];
    const float* b2    = (const float*)d_in[17];
    const float* Wfc   = (const float*)d_in[18];
    const float* bfc   = (const float*)d_in[19];

    const int N = in_sizes[0];
    const int E = in_sizes[1];
    const int T = in_sizes[3];

    char* w = (char*)d_ws;
    size_t off = 0;
    auto alloc = [&](size_t bytes) {
        void* p = w + off;
        off += (bytes + 255) & ~(size_t)255;
        return p;
    };
    bf16_t* xb     = (bf16_t*)alloc((size_t)(N + 64) * DMODEL * 2);
    float*  rn     = (float*) alloc((size_t)E * 3 * 4);
    float*  bl     = (float*) alloc(((size_t)E + 64) * 4);
    int*    cnt    = (int*)   alloc((size_t)E * 4);
    int*    rowp   = (int*)   alloc(((size_t)E + 1) * 4);
    int*    bsum   = (int*)   alloc(4096);
    int2*   packed = (int2*)  alloc((size_t)T * 8);
    int*    ecnt   = (int*)   alloc((size_t)N * 4);
    int*    erowp  = (int*)   alloc(((size_t)N + 1) * 4);
    int*    eord   = (int*)   alloc((size_t)E * 4);
    float*  xs     = (float*) alloc((size_t)N * DM * 4);
    float*  xd     = (float*) alloc((size_t)N * DM * 4);
    bf16_t* xij    = (bf16_t*)alloc((size_t)E * DM * 2);
    bf16_t* msg    = (bf16_t*)alloc((size_t)E * DM * 2);
    bf16_t* ft     = (bf16_t*)alloc((size_t)(N + 64) * DM * 2);
    bf16_t* hb     = (bf16_t*)alloc((size_t)(N + 64) * HDIM * 2);
    bf16_t* W1t    = (bf16_t*)alloc((size_t)3 * HDIM * DM * 2);
    bf16_t* W2t    = (bf16_t*)alloc((size_t)3 * DMODEL * HDIM * 2);
    bf16_t* Wedgt  = (bf16_t*)alloc((size_t)3 * DM * DMODEL * 2);
    bf16_t* Wst    = (bf16_t*)alloc((size_t)3 * DM * DMODEL * 2);
    bf16_t* Wdt    = (bf16_t*)alloc((size_t)3 * DM * DMODEL * 2);
    float*  accs   = (float*) alloc(64);
    (void)ws_size; (void)n_in; (void)out_size;

    const int nbScanE = (E + 255) / 256;
    const int nbScanN = (N + 255) / 256;

    // ---- setup (layer-invariant) ----
    k_embed<<<N, 256, 0, stream>>>(an, emb, xb);
    k_edge_geom<<<(E + 255) / 256, 256, 0, stream>>>(r, bl, rn, E);
    for (int l = 0; l < 3; ++l) {
        k_castT<<<dim3(DM / 32, HDIM / 32), 256, 0, stream>>>(
            W1 + (size_t)l * DM * HDIM, W1t + (size_t)l * HDIM * DM, DM, HDIM);
        k_castT<<<dim3(HDIM / 32, DMODEL / 32), 256, 0, stream>>>(
            W2 + (size_t)l * HDIM * DMODEL, W2t + (size_t)l * DMODEL * HDIM,
            HDIM, DMODEL);
        k_castT<<<dim3(DMODEL / 32, DM / 32), 256, 0, stream>>>(
            Wedge + (size_t)l * DMODEL * DM, Wedgt + (size_t)l * DM * DMODEL,
            DMODEL, DM);
        k_castT<<<dim3(DMODEL / 32, DM / 32), 256, 0, stream>>>(
            Wsrc + (size_t)l * DMODEL * DM, Wst + (size_t)l * DM * DMODEL,
            DMODEL, DM);
        k_castT<<<dim3(DMODEL / 32, DM / 32), 256, 0, stream>>>(
            Wdst + (size_t)l * DMODEL * DM, Wdt + (size_t)l * DM * DMODEL,
            DMODEL, DM);
    }
    // triplet CSR by t_dst
    hipMemsetAsync(cnt, 0, (size_t)E * 4, stream);
    k_hist<<<(T + 255) / 256, 256, 0, stream>>>(td, cnt, T);
    k_scan_part<<<nbScanE, 256, 0, stream>>>(cnt, bsum, E);
    k_scan_mid<<<1, 1024, 0, stream>>>(bsum, nbScanE);
    k_scan_final<<<nbScanE, 256, 0, stream>>>(cnt, bsum, rowp, E, T);
    hipMemsetAsync(cnt, 0, (size_t)E * 4, stream);
    k_scatter<<<(T + 255) / 256, 256, 0, stream>>>(ts, td, rowp, cnt, rn,
                                                   packed, T);
    // edge CSR by gd
    hipMemsetAsync(ecnt, 0, (size_t)N * 4, stream);
    k_hist<<<(E + 255) / 256, 256, 0, stream>>>(gd, ecnt, E);
    k_scan_part<<<nbScanN, 256, 0, stream>>>(ecnt, bsum, N);
    k_scan_mid<<<1, 1024, 0, stream>>>(bsum, nbScanN);
    k_scan_final<<<nbScanN, 256, 0, stream>>>(ecnt, bsum, erowp, N, E);
    hipMemsetAsync(ecnt, 0, (size_t)N * 4, stream);
    k_escatter<<<(E + 255) / 256, 256, 0, stream>>>(gd, erowp, ecnt, eord, E);

    // ---- layers ----
    for (int l = 0; l < 3; ++l) {
        k_node_proj<<<(N + 63) / 64, 256, 0, stream>>>(
            xb, Wst + (size_t)l * DM * DMODEL, bsrc + l * DM,
            Wdt + (size_t)l * DM * DMODEL, bdst + l * DM, xs, xd, N);
        k_xij<<<(E + 63) / 64, 256, 0, stream>>>(
            bl, Wedgt + (size_t)l * DM * DMODEL, bedge + l * DM,
            xs, xd, gs, gd, xij, E);
        k_edge_attn<<<(E * 16 + 255) / 256, 256, 0, stream>>>(
            xij, packed, rowp, attn + l * DM, msg, E);
        k_aggregate<<<(N * 16 + 255) / 256, 256, 0, stream>>>(
            msg, erowp, eord, ft, N);
        k_ffn1<<<dim3((N + 63) / 64, HDIM / 64), 256, 0, stream>>>(
            ft, W1t + (size_t)l * HDIM * DM, b1 + l * HDIM, hb, N);
        k_ffn2<<<dim3((N + 63) / 64, DMODEL / 64), 256, 0, stream>>>(
            hb, W2t + (size_t)l * DMODEL * HDIM, b2 + l * DMODEL, xb, N);
    }

    // ---- output head ----
    hipMemsetAsync(accs, 0, 4, stream);
    k_out_reduce<<<120, 256, 0, stream>>>(xb, Wfc, accs, N * DMODEL);
    k_out_final<<<1, 1, 0, stream>>>(accs, bfc, (float*)d_out, 1.0f / (float)N);
}